// Round 3
// baseline (2470.057 us; speedup 1.0000x reference)
//
#include <hip/hip_runtime.h>
#include <math.h>

#define NN 50000
#define EE 800000
#define RR 4
#define FF 256
#define HH 128
#define OO 32
#define BB 10000
#define EPSV 1e-5f
#define NB 196      // node buckets of 256 nodes
#define BCAP 6144   // max edges per bucket (mean 4096, sigma ~64)

typedef __bf16 bf16_t;
typedef __attribute__((ext_vector_type(8))) bf16_t bf16x8;
typedef __attribute__((ext_vector_type(4))) float f32x4;

__device__ __forceinline__ unsigned short f2bf(float f) {
    unsigned int u = __float_as_uint(f);
    u += 0x7fff + ((u >> 16) & 1);
    return (unsigned short)(u >> 16);
}
__device__ __forceinline__ float bf2f(unsigned short s) {
    return __uint_as_float(((unsigned int)s) << 16);
}
__device__ __forceinline__ void load_lds16(const void* g, void* l) {
    __builtin_amdgcn_global_load_lds(
        (const __attribute__((address_space(1))) unsigned int*)g,
        (__attribute__((address_space(3))) unsigned int*)l, 16, 0, 0);
}

// ---------------- conversions ----------------

__global__ void k_cvt_feat(const float* __restrict__ in, ushort* __restrict__ out) {
    int idx = blockIdx.x * 256 + threadIdx.x;
    const float4* p = (const float4*)in + (size_t)idx * 2;
    float4 a = p[0], b = p[1];
    uint4 o;
    o.x = (unsigned)f2bf(a.x) | ((unsigned)f2bf(a.y) << 16);
    o.y = (unsigned)f2bf(a.z) | ((unsigned)f2bf(a.w) << 16);
    o.z = (unsigned)f2bf(b.x) | ((unsigned)f2bf(b.y) << 16);
    o.w = (unsigned)f2bf(b.z) | ((unsigned)f2bf(b.w) << 16);
    ((uint4*)out)[idx] = o;
}

__global__ void k_cvt_w1(const float* __restrict__ in, ushort* __restrict__ out) {
    int idx = blockIdx.x * 256 + threadIdx.x;
    if (idx >= RR * FF * HH) return;
    int r = idx >> 15, k = (idx >> 7) & 255, n = idx & 127;
    out[r * (HH * FF) + n * FF + k] = f2bf(in[idx]);
}

__global__ void k_cvt_w2(const float* __restrict__ in, ushort* __restrict__ out) {
    int idx = blockIdx.x * 256 + threadIdx.x;
    if (idx >= RR * HH * OO) return;
    int r = idx >> 12, k = (idx >> 5) & 127, n = idx & 31;
    out[r * (OO * HH) + n * HH + k] = f2bf(in[idx]);
}

// ---------------- CSR build (bucketed) ----------------

// phase 1: stream edges, count degrees, scatter (src,dst) into node-range buckets
__global__ void k_bucket(const int* __restrict__ edges, int* __restrict__ deg,
                         int* __restrict__ bcnt, uint2* __restrict__ bdata) {
    int r = blockIdx.y;
    int e = blockIdx.x * 256 + threadIdx.x;
    if (e >= EE) return;
    int src = edges[(size_t)r * 2 * EE + e];
    int dst = edges[(size_t)r * 2 * EE + EE + e];
    atomicAdd(&deg[r * NN + dst], 1);
    int g = r * NB + (dst >> 8);
    int pos = atomicAdd(&bcnt[g], 1);
    if (pos < BCAP) bdata[(size_t)g * BCAP + pos] = make_uint2((unsigned)src, (unsigned)dst);
}

__global__ void k_scan(const int* __restrict__ deg, int* __restrict__ offs,
                       float* __restrict__ dinv) {
    int r = blockIdx.x;
    int t = threadIdx.x;
    const int C = (NN + 255) / 256;
    __shared__ int s[256];
    int begin = t * C;
    int end = begin + C; if (end > NN) end = NN;
    int sum = 0;
    for (int i = begin; i < end; ++i) sum += deg[r * NN + i];
    s[t] = sum;
    __syncthreads();
    for (int off = 1; off < 256; off <<= 1) {
        int u = (t >= off) ? s[t - off] : 0;
        __syncthreads();
        s[t] += u;
        __syncthreads();
    }
    int run = s[t] - sum;
    for (int i = begin; i < end; ++i) {
        int d = deg[r * NN + i];
        offs[r * (NN + 1) + i] = run;
        dinv[r * NN + i] = rsqrtf((float)(d + 1));
        run += d;
    }
    if (t == 255) offs[r * (NN + 1) + NN] = EE;
}

// phase 2: per-bucket LDS counting sort, coalesced CSR segment write
__global__ __launch_bounds__(256) void k_csr(const uint2* __restrict__ bdata,
                                             const int* __restrict__ bcnt,
                                             const int* __restrict__ offs,
                                             int* __restrict__ csr) {
    int b = blockIdx.x, r = blockIdx.y;
    int g = r * NB + b;
    int t = threadIdx.x;
    int cnt = bcnt[g]; if (cnt > BCAP) cnt = BCAP;
    int n0 = b << 8;
    __shared__ int ldeg[256];
    __shared__ int s[256];
    __shared__ int lcur[256];
    __shared__ int lcsr[BCAP];
    ldeg[t] = 0;
    __syncthreads();
    for (int i = t; i < cnt; i += 256) {
        int d = (int)bdata[(size_t)g * BCAP + i].y - n0;
        atomicAdd(&ldeg[d], 1);
    }
    __syncthreads();
    int v = ldeg[t];
    s[t] = v;
    __syncthreads();
    for (int off = 1; off < 256; off <<= 1) {
        int u = (t >= off) ? s[t - off] : 0;
        __syncthreads();
        s[t] += u;
        __syncthreads();
    }
    lcur[t] = s[t] - v;  // exclusive prefix
    __syncthreads();
    for (int i = t; i < cnt; i += 256) {
        uint2 ed = bdata[(size_t)g * BCAP + i];
        int d = (int)ed.y - n0;
        int pos = atomicAdd(&lcur[d], 1);
        lcsr[pos] = (int)ed.x;
    }
    __syncthreads();
    int base = offs[r * (NN + 1) + n0];
    for (int i = t; i < cnt; i += 256)
        csr[(size_t)r * EE + base + i] = lcsr[i];
}

// ---------------- MFMA GEMM1: C[N][128] = A[N][256] x W1t[128][256]^T ----------------

__global__ __launch_bounds__(256) void k_mm1(const ushort* __restrict__ A,
                                             const ushort* __restrict__ Wt,
                                             ushort* __restrict__ C) {
    __shared__ __align__(16) ushort As[128 * 32];
    __shared__ __align__(16) ushort Bs[128 * 32];
    int tid = threadIdx.x;
    int lane = tid & 63, w = tid >> 6;
    int wm = w >> 1, wn = w & 1;
    int row0 = blockIdx.x * 128;
    int l15 = lane & 15, l4 = lane >> 4;

    f32x4 acc[4][4];
#pragma unroll
    for (int mf = 0; mf < 4; ++mf)
#pragma unroll
        for (int nf = 0; nf < 4; ++nf) acc[mf][nf] = (f32x4)0.f;

    for (int k0 = 0; k0 < FF; k0 += 32) {
#pragma unroll
        for (int i = 0; i < 2; ++i) {
            int chunk = i * 256 + tid;
            int ar = chunk >> 2, as_ = chunk & 3;
            int grow = row0 + ar; if (grow > NN - 1) grow = NN - 1;
            load_lds16(A + (size_t)grow * FF + k0 + as_ * 8,
                       As + (size_t)(i * 256 + w * 64) * 8);
        }
#pragma unroll
        for (int i = 0; i < 2; ++i) {
            int chunk = i * 256 + tid;
            int bn = chunk >> 2, slot = chunk & 3;
            uint4 v = *(const uint4*)(Wt + bn * FF + k0 + slot * 8);
            int sw = slot ^ ((bn >> 1) & 3);
            *(uint4*)(Bs + bn * 32 + sw * 8) = v;
        }
        __syncthreads();
        bf16x8 af[4], bfr[4];
#pragma unroll
        for (int mf = 0; mf < 4; ++mf) {
            int row = wm * 64 + mf * 16 + l15;
            af[mf] = *(const bf16x8*)(As + row * 32 + l4 * 8);
        }
#pragma unroll
        for (int nf = 0; nf < 4; ++nf) {
            int n = wn * 64 + nf * 16 + l15;
            int sw = l4 ^ ((n >> 1) & 3);
            bfr[nf] = *(const bf16x8*)(Bs + n * 32 + sw * 8);
        }
#pragma unroll
        for (int mf = 0; mf < 4; ++mf)
#pragma unroll
            for (int nf = 0; nf < 4; ++nf)
                acc[mf][nf] = __builtin_amdgcn_mfma_f32_16x16x32_bf16(af[mf], bfr[nf], acc[mf][nf], 0, 0, 0);
        __syncthreads();
    }
#pragma unroll
    for (int mf = 0; mf < 4; ++mf) {
#pragma unroll
        for (int nf = 0; nf < 4; ++nf) {
#pragma unroll
            for (int j = 0; j < 4; ++j) {
                int row = row0 + wm * 64 + mf * 16 + l4 * 4 + j;
                if (row < NN)
                    C[(size_t)row * HH + wn * 64 + nf * 16 + l15] = f2bf(acc[mf][nf][j]);
            }
        }
    }
}

// ---------------- MFMA GEMM2: C[N][32] = A[N][128] x W2t[32][128]^T ----------------

__global__ __launch_bounds__(256) void k_mm2(const ushort* __restrict__ A,
                                             const ushort* __restrict__ Wt,
                                             ushort* __restrict__ C) {
    __shared__ __align__(16) ushort As[256 * 32];
    __shared__ __align__(16) ushort Ws2[32 * 128];
    int tid = threadIdx.x;
    int lane = tid & 63, w = tid >> 6;
    int l15 = lane & 15, l4 = lane >> 4;
    int row0 = blockIdx.x * 256;

#pragma unroll
    for (int i = 0; i < 2; ++i) {
        int chunk = i * 256 + tid;
        int n = chunk >> 4, slot = chunk & 15;
        uint4 v = *(const uint4*)(Wt + n * HH + slot * 8);
        int sw = slot ^ (n & 7);
        *(uint4*)(Ws2 + n * HH + sw * 8) = v;
    }

    f32x4 acc[4][2];
#pragma unroll
    for (int mf = 0; mf < 4; ++mf)
#pragma unroll
        for (int nf = 0; nf < 2; ++nf) acc[mf][nf] = (f32x4)0.f;

    for (int k0 = 0; k0 < HH; k0 += 32) {
#pragma unroll
        for (int i = 0; i < 4; ++i) {
            int chunk = i * 256 + tid;
            int ar = chunk >> 2, slot = chunk & 3;
            int grow = row0 + ar; if (grow > NN - 1) grow = NN - 1;
            load_lds16(A + (size_t)grow * HH + k0 + slot * 8,
                       As + (size_t)(i * 256 + w * 64) * 8);
        }
        __syncthreads();
        bf16x8 af[4], bfr[2];
#pragma unroll
        for (int mf = 0; mf < 4; ++mf)
            af[mf] = *(const bf16x8*)(As + (w * 64 + mf * 16 + l15) * 32 + l4 * 8);
#pragma unroll
        for (int nf = 0; nf < 2; ++nf) {
            int n = nf * 16 + l15;
            int slot = (k0 >> 3) + l4;
            int sw = slot ^ (n & 7);
            bfr[nf] = *(const bf16x8*)(Ws2 + n * HH + sw * 8);
        }
#pragma unroll
        for (int mf = 0; mf < 4; ++mf)
#pragma unroll
            for (int nf = 0; nf < 2; ++nf)
                acc[mf][nf] = __builtin_amdgcn_mfma_f32_16x16x32_bf16(af[mf], bfr[nf], acc[mf][nf], 0, 0, 0);
        __syncthreads();
    }
#pragma unroll
    for (int mf = 0; mf < 4; ++mf) {
#pragma unroll
        for (int nf = 0; nf < 2; ++nf) {
#pragma unroll
            for (int j = 0; j < 4; ++j) {
                int row = row0 + w * 64 + mf * 16 + l4 * 4 + j;
                if (row < NN)
                    C[(size_t)row * OO + nf * 16 + l15] = f2bf(acc[mf][nf][j]);
            }
        }
    }
}

// ---------------- aggregation (bf16 in, fp32 out) ----------------

__global__ void k_agg1(const ushort* __restrict__ X, float* __restrict__ Y,
                       const int* __restrict__ offs, const int* __restrict__ csr,
                       const float* __restrict__ dinv) {
    int tid = threadIdx.x;
    int wid = tid >> 6, lane = tid & 63;
    int n = blockIdx.x * 4 + wid;
    if (n >= NN) return;
    int c = lane * 2;
    float ax = 0.f, ay = 0.f;
    int s0 = offs[n], s1 = offs[n + 1];
    for (int e = s0; e < s1; ++e) {
        int s = csr[e];
        float wgt = dinv[s];
        unsigned v = *(const unsigned*)(X + (size_t)s * HH + c);
        ax += wgt * bf2f((ushort)(v & 0xffff));
        ay += wgt * bf2f((ushort)(v >> 16));
    }
    float dn = dinv[n];
    unsigned v = *(const unsigned*)(X + (size_t)n * HH + c);
    ax += dn * bf2f((ushort)(v & 0xffff));
    ay += dn * bf2f((ushort)(v >> 16));
    float2 o; o.x = ax * dn; o.y = ay * dn;
    *(float2*)(Y + (size_t)n * HH + c) = o;
}

__global__ void k_agg2(const ushort* __restrict__ X, float* __restrict__ Y,
                       const int* __restrict__ offs, const int* __restrict__ csr,
                       const float* __restrict__ dinv) {
    int tid = threadIdx.x;
    int wid = tid >> 6, lane = tid & 63;
    int sub = lane >> 5, col = lane & 31;
    int n = blockIdx.x * 8 + wid * 2 + sub;
    if (n >= NN) return;
    float acc = 0.f;
    int s0 = offs[n], s1 = offs[n + 1];
    for (int e = s0; e < s1; ++e) {
        int s = csr[e];
        acc += dinv[s] * bf2f(X[(size_t)s * OO + col]);
    }
    float dn = dinv[n];
    acc += dn * bf2f(X[(size_t)n * OO + col]);
    Y[(size_t)n * OO + col] = acc * dn;
}

// ---------------- batchnorm ----------------

template <int D>
__global__ void k_stats(const float* __restrict__ X, float* __restrict__ partial) {
    constexpr int BY = 256 / D;
    int c = threadIdx.x;
    int ty = threadIdx.y;
    float s = 0.f, ss = 0.f;
    for (int row = blockIdx.x * BY + ty; row < NN; row += gridDim.x * BY) {
        float v = X[(size_t)row * D + c];
        s += v; ss += v * v;
    }
    __shared__ float ls[BY][D];
    __shared__ float lss[BY][D];
    ls[ty][c] = s; lss[ty][c] = ss;
    __syncthreads();
    if (ty == 0) {
#pragma unroll
        for (int y = 1; y < BY; ++y) { s += ls[y][c]; ss += lss[y][c]; }
        partial[blockIdx.x * 2 * D + c] = s;
        partial[blockIdx.x * 2 * D + D + c] = ss;
    }
}

template <int D>
__global__ void k_finalize(const float* __restrict__ partial, const float* __restrict__ g,
                           const float* __restrict__ be, float* __restrict__ ab) {
    int c = threadIdx.x;
    float s = 0.f, ss = 0.f;
    for (int i = 0; i < 256; ++i) {
        s += partial[i * 2 * D + c];
        ss += partial[i * 2 * D + D + c];
    }
    float mean = s / (float)NN;
    float var = ss / (float)NN - mean * mean;
    float rstd = rsqrtf(var + EPSV);
    float a = g[c] * rstd;
    ab[c] = a;
    ab[D + c] = be[c] - mean * a;
}

__global__ void k_apply1(const float* __restrict__ X, const float* __restrict__ ab,
                         ushort* __restrict__ Y) {
    int idx = blockIdx.x * 256 + threadIdx.x;
    if (idx >= NN * HH / 4) return;
    int c4 = idx & 31;
    float4 x = ((const float4*)X)[idx];
    float4 a = ((const float4*)ab)[c4];
    float4 b = ((const float4*)ab)[32 + c4];
    float y0 = fmaxf(a.x * x.x + b.x, 0.f);
    float y1 = fmaxf(a.y * x.y + b.y, 0.f);
    float y2 = fmaxf(a.z * x.z + b.z, 0.f);
    float y3 = fmaxf(a.w * x.w + b.w, 0.f);
    uint2 o;
    o.x = (unsigned)f2bf(y0) | ((unsigned)f2bf(y1) << 16);
    o.y = (unsigned)f2bf(y2) | ((unsigned)f2bf(y3) << 16);
    ((uint2*)Y)[idx] = o;
}

template <int D>
__global__ void k_apply(float* __restrict__ X, const float* __restrict__ ab) {
    constexpr int TOT4 = NN * D / 4;
    int idx = blockIdx.x * blockDim.x + threadIdx.x;
    if (idx >= TOT4) return;
    int c4 = idx % (D / 4);
    float4 x = ((const float4*)X)[idx];
    float4 a = ((const float4*)ab)[c4];
    float4 b = ((const float4*)ab)[D / 4 + c4];
    float4 y;
    y.x = fmaxf(a.x * x.x + b.x, 0.f);
    y.y = fmaxf(a.y * x.y + b.y, 0.f);
    y.z = fmaxf(a.z * x.z + b.z, 0.f);
    y.w = fmaxf(a.w * x.w + b.w, 0.f);
    ((float4*)X)[idx] = y;
}

// ---------------- gather + log_softmax ----------------

__global__ void k_lsm(const float* __restrict__ X, const int* __restrict__ batch,
                      float* __restrict__ out, int r) {
    int tx = threadIdx.x;
    int b = blockIdx.x * blockDim.y + threadIdx.y;
    if (b >= BB) return;
    int node = batch[b];
    float v = X[(size_t)node * OO + tx];
    float m = v;
#pragma unroll
    for (int off = 16; off; off >>= 1) m = fmaxf(m, __shfl_xor(m, off, 32));
    float e = expf(v - m);
    float sum = e;
#pragma unroll
    for (int off = 16; off; off >>= 1) sum += __shfl_xor(sum, off, 32);
    out[(size_t)b * (RR * OO) + r * OO + tx] = v - m - logf(sum);
}

// ---------------- host ----------------

extern "C" void kernel_launch(void* const* d_in, const int* in_sizes, int n_in,
                              void* d_out, int out_size, void* d_ws, size_t ws_size,
                              hipStream_t stream) {
    const float* features = (const float*)d_in[0];
    const int* edges = (const int*)d_in[1];
    const int* batch = (const int*)d_in[2];
    const float* W1 = (const float*)d_in[3];
    const float* g1 = (const float*)d_in[5];
    const float* be1 = (const float*)d_in[6];
    const float* W2 = (const float*)d_in[7];
    const float* g2 = (const float*)d_in[9];
    const float* be2 = (const float*)d_in[10];
    float* out = (float*)d_out;

    char* p = (char*)d_ws;
    auto carve = [&](size_t bytes) {
        void* q = (void*)p;
        p += (bytes + 255) & ~(size_t)255;
        return q;
    };
    ushort* Fbf = (ushort*)carve((size_t)NN * FF * 2);
    ushort* W1t = (ushort*)carve((size_t)RR * FF * HH * 2);
    ushort* W2t = (ushort*)carve((size_t)RR * HH * OO * 2);
    int* deg = (int*)carve((size_t)RR * NN * 4);
    float* dinv = (float*)carve((size_t)RR * NN * 4);
    int* offs = (int*)carve((size_t)RR * (NN + 1) * 4);
    int* bcnt = (int*)carve((size_t)RR * NB * 4);
    int* csr = (int*)carve((size_t)RR * EE * 4);
    ushort* bufAh = (ushort*)carve((size_t)NN * HH * 2);
    float* bufB = (float*)carve((size_t)NN * HH * 4);
    ushort* bufBh = (ushort*)carve((size_t)NN * HH * 2);
    ushort* bufCh = (ushort*)carve((size_t)NN * OO * 2);
    float* bufD = (float*)carve((size_t)NN * OO * 4);
    float* partial = (float*)carve((size_t)256 * 2 * HH * 4);
    float* ab = (float*)carve((size_t)2 * HH * 4);
    // bucket staging aliases bufAh..bufBh (only live before mm1 runs):
    // need RR*NB*BCAP*8 = 38.5 MB; bufAh+bufB+bufBh = 51.2 MB
    uint2* bdata = (uint2*)bufAh;

    k_cvt_feat<<<NN * FF / 8 / 256, 256, 0, stream>>>(features, Fbf);
    k_cvt_w1<<<(RR * FF * HH + 255) / 256, 256, 0, stream>>>(W1, W1t);
    k_cvt_w2<<<(RR * HH * OO + 255) / 256, 256, 0, stream>>>(W2, W2t);

    hipMemsetAsync(deg, 0, (size_t)RR * NN * 4, stream);
    hipMemsetAsync(bcnt, 0, (size_t)RR * NB * 4, stream);
    k_bucket<<<dim3((EE + 255) / 256, RR), 256, 0, stream>>>(edges, deg, bcnt, bdata);
    k_scan<<<RR, 256, 0, stream>>>(deg, offs, dinv);
    k_csr<<<dim3(NB, RR), 256, 0, stream>>>(bdata, bcnt, offs, csr);

    for (int r = 0; r < RR; ++r) {
        const int* offs_r = offs + r * (NN + 1);
        const int* csr_r = csr + (size_t)r * EE;
        const float* dinv_r = dinv + (size_t)r * NN;

        k_mm1<<<(NN + 127) / 128, 256, 0, stream>>>(Fbf, W1t + (size_t)r * FF * HH, bufAh);
        k_agg1<<<(NN + 3) / 4, 256, 0, stream>>>(bufAh, bufB, offs_r, csr_r, dinv_r);
        k_stats<HH><<<256, dim3(HH, 256 / HH), 0, stream>>>(bufB, partial);
        k_finalize<HH><<<1, HH, 0, stream>>>(partial, g1 + r * HH, be1 + r * HH, ab);
        k_apply1<<<(NN * HH / 4 + 255) / 256, 256, 0, stream>>>(bufB, ab, bufBh);

        k_mm2<<<(NN + 255) / 256, 256, 0, stream>>>(bufBh, W2t + (size_t)r * HH * OO, bufCh);
        k_agg2<<<(NN + 7) / 8, 256, 0, stream>>>(bufCh, bufD, offs_r, csr_r, dinv_r);
        k_stats<OO><<<256, dim3(OO, 256 / OO), 0, stream>>>(bufD, partial);
        k_finalize<OO><<<1, OO, 0, stream>>>(partial, g2 + r * OO, be2 + r * OO, ab);
        k_apply<OO><<<(NN * OO / 4 + 255) / 256, 256, 0, stream>>>(bufD, ab);

        k_lsm<<<(BB + 7) / 8, dim3(32, 8), 0, stream>>>(bufD, batch, out, r);
    }
}

// Round 4
// 1091.189 us; speedup vs baseline: 2.2636x; 2.2636x over previous
//
#include <hip/hip_runtime.h>
#include <math.h>

#define NN 50000
#define EE 800000
#define RR 4
#define FF 256
#define HH 128
#define OO 32
#define BB 10000
#define EPSV 1e-5f

#define NSEG 128      // pass-A blocks per relation
#define CH   (EE / NSEG)   // 6250 edges per block
#define NBK  64       // node buckets
#define BNODE 784     // nodes per bucket (64*784 = 50176 >= NN)
#define SCAP 160      // capacity per (block,bucket) segment; mean 98, +6.3 sigma
#define LCSR_CAP 16384

typedef __bf16 bf16_t;
typedef __attribute__((ext_vector_type(8))) bf16_t bf16x8;
typedef __attribute__((ext_vector_type(4))) float f32x4;

__device__ __forceinline__ unsigned short f2bf(float f) {
    unsigned int u = __float_as_uint(f);
    u += 0x7fff + ((u >> 16) & 1);
    return (unsigned short)(u >> 16);
}
__device__ __forceinline__ float bf2f(unsigned short s) {
    return __uint_as_float(((unsigned int)s) << 16);
}
__device__ __forceinline__ void load_lds16(const void* g, void* l) {
    __builtin_amdgcn_global_load_lds(
        (const __attribute__((address_space(1))) unsigned int*)g,
        (__attribute__((address_space(3))) unsigned int*)l, 16, 0, 0);
}

// ---------------- conversions ----------------

__global__ void k_cvt_feat(const float* __restrict__ in, ushort* __restrict__ out) {
    int idx = blockIdx.x * 256 + threadIdx.x;
    const float4* p = (const float4*)in + (size_t)idx * 2;
    float4 a = p[0], b = p[1];
    uint4 o;
    o.x = (unsigned)f2bf(a.x) | ((unsigned)f2bf(a.y) << 16);
    o.y = (unsigned)f2bf(a.z) | ((unsigned)f2bf(a.w) << 16);
    o.z = (unsigned)f2bf(b.x) | ((unsigned)f2bf(b.y) << 16);
    o.w = (unsigned)f2bf(b.z) | ((unsigned)f2bf(b.w) << 16);
    ((uint4*)out)[idx] = o;
}

__global__ void k_cvt_w1(const float* __restrict__ in, ushort* __restrict__ out) {
    int idx = blockIdx.x * 256 + threadIdx.x;
    if (idx >= RR * FF * HH) return;
    int r = idx >> 15, k = (idx >> 7) & 255, n = idx & 127;
    out[r * (HH * FF) + n * FF + k] = f2bf(in[idx]);
}

__global__ void k_cvt_w2(const float* __restrict__ in, ushort* __restrict__ out) {
    int idx = blockIdx.x * 256 + threadIdx.x;
    if (idx >= RR * HH * OO) return;
    int r = idx >> 12, k = (idx >> 5) & 127, n = idx & 31;
    out[r * (OO * HH) + n * HH + k] = f2bf(in[idx]);
}

// ---------------- CSR build: block-private bucket partition ----------------

// Pass A: each block scatters its private 6250-edge chunk into 64 block-private
// bucket segments. Cursors in LDS (no global atomics); writes land in
// block-private lines -> L2 write-combining.
__global__ __launch_bounds__(256) void k_passA(const int* __restrict__ edges,
                                               uint2* __restrict__ seg,
                                               int* __restrict__ cnt) {
    int r = blockIdx.y, blk = blockIdx.x, t = threadIdx.x;
    __shared__ int lcur[NBK];
    if (t < NBK) lcur[t] = 0;
    __syncthreads();
    const int* srcp = edges + (size_t)r * 2 * EE + blk * CH;
    const int* dstp = srcp + EE;
    uint2* segbase = seg + (size_t)(r * NSEG + blk) * NBK * SCAP;
    for (int i = t; i < CH; i += 256) {
        int s = srcp[i], d = dstp[i];
        int b = d / BNODE;
        int pos = atomicAdd(&lcur[b], 1);
        if (pos < SCAP) segbase[b * SCAP + pos] = make_uint2((unsigned)s, (unsigned)d);
    }
    __syncthreads();
    if (t < NBK) cnt[(r * NSEG + blk) * NBK + t] = min(lcur[t], SCAP);
}

// bucket base offsets: exclusive prefix of per-bucket totals (64 values / relation)
__global__ void k_bbase(const int* __restrict__ cnt, int* __restrict__ bbase,
                        int* __restrict__ offs) {
    int r = blockIdx.x, t = threadIdx.x;  // 64 threads = 1 wave
    int sum = 0;
    for (int s = 0; s < NSEG; ++s) sum += cnt[(r * NSEG + s) * NBK + t];
    int v = sum;
    for (int off = 1; off < 64; off <<= 1) {
        int u = __shfl_up(v, off, 64);
        if (t >= off) v += u;
    }
    bbase[r * (NBK + 1) + t] = v - sum;
    if (t == 63) {
        bbase[r * (NBK + 1) + NBK] = v;
        offs[r * (NN + 1) + NN] = v;  // total edge count (== EE barring overflow)
    }
}

// Pass B: per (bucket, relation): LDS counting sort -> offs/dinv/CSR, all coalesced.
__global__ __launch_bounds__(256) void k_passB(const uint2* __restrict__ seg,
                                               const int* __restrict__ cnt,
                                               const int* __restrict__ bbase,
                                               int* __restrict__ csr,
                                               int* __restrict__ offs,
                                               float* __restrict__ dinv) {
    int b = blockIdx.x, r = blockIdx.y, t = threadIdx.x;
    __shared__ int ldeg[1024];
    __shared__ int lpre[1024];
    __shared__ int tsum[256];
    __shared__ int scnt[NSEG];
    __shared__ int lcsr[LCSR_CAP];
    for (int i = t; i < 1024; i += 256) ldeg[i] = 0;
    for (int i = t; i < NSEG; i += 256) scnt[i] = cnt[(r * NSEG + i) * NBK + b];
    __syncthreads();
    int n0 = b * BNODE;
    // count pass
    for (int s = 0; s < NSEG; ++s) {
        const uint2* sp = seg + ((size_t)(r * NSEG + s) * NBK + b) * SCAP;
        int c = scnt[s];
        for (int i = t; i < c; i += 256)
            atomicAdd(&ldeg[(int)sp[i].y - n0], 1);
    }
    __syncthreads();
    // prefix over 1024 (784 live): 4 elems/thread + 256-wide scan
    int b4 = t * 4;
    int a0 = ldeg[b4], a1 = ldeg[b4 + 1], a2 = ldeg[b4 + 2], a3 = ldeg[b4 + 3];
    int tl = a0 + a1 + a2 + a3;
    tsum[t] = tl;
    __syncthreads();
    for (int off = 1; off < 256; off <<= 1) {
        int u = (t >= off) ? tsum[t - off] : 0;
        __syncthreads();
        tsum[t] += u;
        __syncthreads();
    }
    int ex = tsum[t] - tl;
    lpre[b4] = ex; lpre[b4 + 1] = ex + a0; lpre[b4 + 2] = ex + a0 + a1; lpre[b4 + 3] = ex + a0 + a1 + a2;
    __syncthreads();
    int gbase = bbase[r * (NBK + 1) + b];
    int btot = bbase[r * (NBK + 1) + b + 1] - gbase;
    for (int i = t; i < BNODE; i += 256) {
        int n = n0 + i;
        if (n < NN) {
            offs[r * (NN + 1) + n] = gbase + lpre[i];
            dinv[r * NN + n] = rsqrtf((float)(ldeg[i] + 1));
        }
    }
    __syncthreads();
    // scatter pass (lpre becomes cursors)
    for (int s = 0; s < NSEG; ++s) {
        const uint2* sp = seg + ((size_t)(r * NSEG + s) * NBK + b) * SCAP;
        int c = scnt[s];
        for (int i = t; i < c; i += 256) {
            uint2 e = sp[i];
            int p = atomicAdd(&lpre[(int)e.y - n0], 1);
            if (p < LCSR_CAP) lcsr[p] = (int)e.x;
        }
    }
    __syncthreads();
    for (int i = t; i < btot; i += 256)
        csr[(size_t)r * EE + gbase + i] = lcsr[i];
}

// ---------------- MFMA GEMM1: C[N][128] = A[N][256] x W1t[128][256]^T ----------------

__global__ __launch_bounds__(256) void k_mm1(const ushort* __restrict__ A,
                                             const ushort* __restrict__ Wt,
                                             ushort* __restrict__ C) {
    __shared__ __align__(16) ushort As[128 * 32];
    __shared__ __align__(16) ushort Bs[128 * 32];
    int tid = threadIdx.x;
    int lane = tid & 63, w = tid >> 6;
    int wm = w >> 1, wn = w & 1;
    int row0 = blockIdx.x * 128;
    int l15 = lane & 15, l4 = lane >> 4;

    f32x4 acc[4][4];
#pragma unroll
    for (int mf = 0; mf < 4; ++mf)
#pragma unroll
        for (int nf = 0; nf < 4; ++nf) acc[mf][nf] = (f32x4)0.f;

    for (int k0 = 0; k0 < FF; k0 += 32) {
#pragma unroll
        for (int i = 0; i < 2; ++i) {
            int chunk = i * 256 + tid;
            int ar = chunk >> 2, as_ = chunk & 3;
            int grow = row0 + ar; if (grow > NN - 1) grow = NN - 1;
            load_lds16(A + (size_t)grow * FF + k0 + as_ * 8,
                       As + (size_t)(i * 256 + w * 64) * 8);
        }
#pragma unroll
        for (int i = 0; i < 2; ++i) {
            int chunk = i * 256 + tid;
            int bn = chunk >> 2, slot = chunk & 3;
            uint4 v = *(const uint4*)(Wt + bn * FF + k0 + slot * 8);
            int sw = slot ^ ((bn >> 1) & 3);
            *(uint4*)(Bs + bn * 32 + sw * 8) = v;
        }
        __syncthreads();
        bf16x8 af[4], bfr[4];
#pragma unroll
        for (int mf = 0; mf < 4; ++mf) {
            int row = wm * 64 + mf * 16 + l15;
            af[mf] = *(const bf16x8*)(As + row * 32 + l4 * 8);
        }
#pragma unroll
        for (int nf = 0; nf < 4; ++nf) {
            int n = wn * 64 + nf * 16 + l15;
            int sw = l4 ^ ((n >> 1) & 3);
            bfr[nf] = *(const bf16x8*)(Bs + n * 32 + sw * 8);
        }
#pragma unroll
        for (int mf = 0; mf < 4; ++mf)
#pragma unroll
            for (int nf = 0; nf < 4; ++nf)
                acc[mf][nf] = __builtin_amdgcn_mfma_f32_16x16x32_bf16(af[mf], bfr[nf], acc[mf][nf], 0, 0, 0);
        __syncthreads();
    }
#pragma unroll
    for (int mf = 0; mf < 4; ++mf) {
#pragma unroll
        for (int nf = 0; nf < 4; ++nf) {
#pragma unroll
            for (int j = 0; j < 4; ++j) {
                int row = row0 + wm * 64 + mf * 16 + l4 * 4 + j;
                if (row < NN)
                    C[(size_t)row * HH + wn * 64 + nf * 16 + l15] = f2bf(acc[mf][nf][j]);
            }
        }
    }
}

// ---------------- MFMA GEMM2: C[N][32] = A[N][128] x W2t[32][128]^T ----------------

__global__ __launch_bounds__(256) void k_mm2(const ushort* __restrict__ A,
                                             const ushort* __restrict__ Wt,
                                             ushort* __restrict__ C) {
    __shared__ __align__(16) ushort As[256 * 32];
    __shared__ __align__(16) ushort Ws2[32 * 128];
    int tid = threadIdx.x;
    int lane = tid & 63, w = tid >> 6;
    int l15 = lane & 15, l4 = lane >> 4;
    int row0 = blockIdx.x * 256;

#pragma unroll
    for (int i = 0; i < 2; ++i) {
        int chunk = i * 256 + tid;
        int n = chunk >> 4, slot = chunk & 15;
        uint4 v = *(const uint4*)(Wt + n * HH + slot * 8);
        int sw = slot ^ (n & 7);
        *(uint4*)(Ws2 + n * HH + sw * 8) = v;
    }

    f32x4 acc[4][2];
#pragma unroll
    for (int mf = 0; mf < 4; ++mf)
#pragma unroll
        for (int nf = 0; nf < 2; ++nf) acc[mf][nf] = (f32x4)0.f;

    for (int k0 = 0; k0 < HH; k0 += 32) {
#pragma unroll
        for (int i = 0; i < 4; ++i) {
            int chunk = i * 256 + tid;
            int ar = chunk >> 2, slot = chunk & 3;
            int grow = row0 + ar; if (grow > NN - 1) grow = NN - 1;
            load_lds16(A + (size_t)grow * HH + k0 + slot * 8,
                       As + (size_t)(i * 256 + w * 64) * 8);
        }
        __syncthreads();
        bf16x8 af[4], bfr[2];
#pragma unroll
        for (int mf = 0; mf < 4; ++mf)
            af[mf] = *(const bf16x8*)(As + (w * 64 + mf * 16 + l15) * 32 + l4 * 8);
#pragma unroll
        for (int nf = 0; nf < 2; ++nf) {
            int n = nf * 16 + l15;
            int slot = (k0 >> 3) + l4;
            int sw = slot ^ (n & 7);
            bfr[nf] = *(const bf16x8*)(Ws2 + n * HH + sw * 8);
        }
#pragma unroll
        for (int mf = 0; mf < 4; ++mf)
#pragma unroll
            for (int nf = 0; nf < 2; ++nf)
                acc[mf][nf] = __builtin_amdgcn_mfma_f32_16x16x32_bf16(af[mf], bfr[nf], acc[mf][nf], 0, 0, 0);
        __syncthreads();
    }
#pragma unroll
    for (int mf = 0; mf < 4; ++mf) {
#pragma unroll
        for (int nf = 0; nf < 2; ++nf) {
#pragma unroll
            for (int j = 0; j < 4; ++j) {
                int row = row0 + w * 64 + mf * 16 + l4 * 4 + j;
                if (row < NN)
                    C[(size_t)row * OO + nf * 16 + l15] = f2bf(acc[mf][nf][j]);
            }
        }
    }
}

// ---------------- aggregation (bf16 in, fp32 out) ----------------

__global__ void k_agg1(const ushort* __restrict__ X, float* __restrict__ Y,
                       const int* __restrict__ offs, const int* __restrict__ csr,
                       const float* __restrict__ dinv) {
    int tid = threadIdx.x;
    int wid = tid >> 6, lane = tid & 63;
    int n = blockIdx.x * 4 + wid;
    if (n >= NN) return;
    int c = lane * 2;
    float ax = 0.f, ay = 0.f;
    int s0 = offs[n], s1 = offs[n + 1];
    for (int e = s0; e < s1; ++e) {
        int s = csr[e];
        float wgt = dinv[s];
        unsigned v = *(const unsigned*)(X + (size_t)s * HH + c);
        ax += wgt * bf2f((ushort)(v & 0xffff));
        ay += wgt * bf2f((ushort)(v >> 16));
    }
    float dn = dinv[n];
    unsigned v = *(const unsigned*)(X + (size_t)n * HH + c);
    ax += dn * bf2f((ushort)(v & 0xffff));
    ay += dn * bf2f((ushort)(v >> 16));
    float2 o; o.x = ax * dn; o.y = ay * dn;
    *(float2*)(Y + (size_t)n * HH + c) = o;
}

__global__ void k_agg2(const ushort* __restrict__ X, float* __restrict__ Y,
                       const int* __restrict__ offs, const int* __restrict__ csr,
                       const float* __restrict__ dinv) {
    int tid = threadIdx.x;
    int wid = tid >> 6, lane = tid & 63;
    int sub = lane >> 5, col = lane & 31;
    int n = blockIdx.x * 8 + wid * 2 + sub;
    if (n >= NN) return;
    float acc = 0.f;
    int s0 = offs[n], s1 = offs[n + 1];
    for (int e = s0; e < s1; ++e) {
        int s = csr[e];
        acc += dinv[s] * bf2f(X[(size_t)s * OO + col]);
    }
    float dn = dinv[n];
    acc += dn * bf2f(X[(size_t)n * OO + col]);
    Y[(size_t)n * OO + col] = acc * dn;
}

// ---------------- batchnorm ----------------

template <int D>
__global__ void k_stats(const float* __restrict__ X, float* __restrict__ partial) {
    constexpr int BY = 256 / D;
    int c = threadIdx.x;
    int ty = threadIdx.y;
    float s = 0.f, ss = 0.f;
    for (int row = blockIdx.x * BY + ty; row < NN; row += gridDim.x * BY) {
        float v = X[(size_t)row * D + c];
        s += v; ss += v * v;
    }
    __shared__ float ls[BY][D];
    __shared__ float lss[BY][D];
    ls[ty][c] = s; lss[ty][c] = ss;
    __syncthreads();
    if (ty == 0) {
#pragma unroll
        for (int y = 1; y < BY; ++y) { s += ls[y][c]; ss += lss[y][c]; }
        partial[blockIdx.x * 2 * D + c] = s;
        partial[blockIdx.x * 2 * D + D + c] = ss;
    }
}

template <int D>
__global__ void k_finalize(const float* __restrict__ partial, const float* __restrict__ g,
                           const float* __restrict__ be, float* __restrict__ ab) {
    int c = threadIdx.x;
    float s = 0.f, ss = 0.f;
    for (int i = 0; i < 256; ++i) {
        s += partial[i * 2 * D + c];
        ss += partial[i * 2 * D + D + c];
    }
    float mean = s / (float)NN;
    float var = ss / (float)NN - mean * mean;
    float rstd = rsqrtf(var + EPSV);
    float a = g[c] * rstd;
    ab[c] = a;
    ab[D + c] = be[c] - mean * a;
}

__global__ void k_apply1(const float* __restrict__ X, const float* __restrict__ ab,
                         ushort* __restrict__ Y) {
    int idx = blockIdx.x * 256 + threadIdx.x;
    if (idx >= NN * HH / 4) return;
    int c4 = idx & 31;
    float4 x = ((const float4*)X)[idx];
    float4 a = ((const float4*)ab)[c4];
    float4 b = ((const float4*)ab)[32 + c4];
    float y0 = fmaxf(a.x * x.x + b.x, 0.f);
    float y1 = fmaxf(a.y * x.y + b.y, 0.f);
    float y2 = fmaxf(a.z * x.z + b.z, 0.f);
    float y3 = fmaxf(a.w * x.w + b.w, 0.f);
    uint2 o;
    o.x = (unsigned)f2bf(y0) | ((unsigned)f2bf(y1) << 16);
    o.y = (unsigned)f2bf(y2) | ((unsigned)f2bf(y3) << 16);
    ((uint2*)Y)[idx] = o;
}

template <int D>
__global__ void k_apply(float* __restrict__ X, const float* __restrict__ ab) {
    constexpr int TOT4 = NN * D / 4;
    int idx = blockIdx.x * blockDim.x + threadIdx.x;
    if (idx >= TOT4) return;
    int c4 = idx % (D / 4);
    float4 x = ((const float4*)X)[idx];
    float4 a = ((const float4*)ab)[c4];
    float4 b = ((const float4*)ab)[D / 4 + c4];
    float4 y;
    y.x = fmaxf(a.x * x.x + b.x, 0.f);
    y.y = fmaxf(a.y * x.y + b.y, 0.f);
    y.z = fmaxf(a.z * x.z + b.z, 0.f);
    y.w = fmaxf(a.w * x.w + b.w, 0.f);
    ((float4*)X)[idx] = y;
}

// ---------------- gather + log_softmax ----------------

__global__ void k_lsm(const float* __restrict__ X, const int* __restrict__ batch,
                      float* __restrict__ out, int r) {
    int tx = threadIdx.x;
    int b = blockIdx.x * blockDim.y + threadIdx.y;
    if (b >= BB) return;
    int node = batch[b];
    float v = X[(size_t)node * OO + tx];
    float m = v;
#pragma unroll
    for (int off = 16; off; off >>= 1) m = fmaxf(m, __shfl_xor(m, off, 32));
    float e = expf(v - m);
    float sum = e;
#pragma unroll
    for (int off = 16; off; off >>= 1) sum += __shfl_xor(sum, off, 32);
    out[(size_t)b * (RR * OO) + r * OO + tx] = v - m - logf(sum);
}

// ---------------- host ----------------

extern "C" void kernel_launch(void* const* d_in, const int* in_sizes, int n_in,
                              void* d_out, int out_size, void* d_ws, size_t ws_size,
                              hipStream_t stream) {
    const float* features = (const float*)d_in[0];
    const int* edges = (const int*)d_in[1];
    const int* batch = (const int*)d_in[2];
    const float* W1 = (const float*)d_in[3];
    const float* g1 = (const float*)d_in[5];
    const float* be1 = (const float*)d_in[6];
    const float* W2 = (const float*)d_in[7];
    const float* g2 = (const float*)d_in[9];
    const float* be2 = (const float*)d_in[10];
    float* out = (float*)d_out;

    char* p = (char*)d_ws;
    auto carve = [&](size_t bytes) {
        void* q = (void*)p;
        p += (bytes + 255) & ~(size_t)255;
        return q;
    };
    ushort* Fbf = (ushort*)carve((size_t)NN * FF * 2);
    ushort* W1t = (ushort*)carve((size_t)RR * FF * HH * 2);
    ushort* W2t = (ushort*)carve((size_t)RR * HH * OO * 2);
    float* dinv = (float*)carve((size_t)RR * NN * 4);
    int* offs = (int*)carve((size_t)RR * (NN + 1) * 4);
    int* cnt = (int*)carve((size_t)RR * NSEG * NBK * 4);
    int* bbase = (int*)carve((size_t)RR * (NBK + 1) * 4);
    int* csr = (int*)carve((size_t)RR * EE * 4);
    ushort* bufAh = (ushort*)carve((size_t)NN * HH * 2);
    float* bufB = (float*)carve((size_t)NN * HH * 4);
    ushort* bufBh = (ushort*)carve((size_t)NN * HH * 2);
    ushort* bufCh = (ushort*)carve((size_t)NN * OO * 2);
    float* bufD = (float*)carve((size_t)NN * OO * 4);
    float* partial = (float*)carve((size_t)256 * 2 * HH * 4);
    float* ab = (float*)carve((size_t)2 * HH * 4);
    // seg staging (RR*NSEG*NBK*SCAP*8B = 41.9 MB) aliases bufAh+bufB+bufBh
    // (51.2 MB, only written after the CSR build completes in-stream)
    uint2* seg = (uint2*)bufAh;

    k_cvt_feat<<<NN * FF / 8 / 256, 256, 0, stream>>>(features, Fbf);
    k_cvt_w1<<<(RR * FF * HH + 255) / 256, 256, 0, stream>>>(W1, W1t);
    k_cvt_w2<<<(RR * HH * OO + 255) / 256, 256, 0, stream>>>(W2, W2t);

    k_passA<<<dim3(NSEG, RR), 256, 0, stream>>>(edges, seg, cnt);
    k_bbase<<<RR, 64, 0, stream>>>(cnt, bbase, offs);
    k_passB<<<dim3(NBK, RR), 256, 0, stream>>>(seg, cnt, bbase, csr, offs, dinv);

    for (int r = 0; r < RR; ++r) {
        const int* offs_r = offs + r * (NN + 1);
        const int* csr_r = csr + (size_t)r * EE;
        const float* dinv_r = dinv + (size_t)r * NN;

        k_mm1<<<(NN + 127) / 128, 256, 0, stream>>>(Fbf, W1t + (size_t)r * FF * HH, bufAh);
        k_agg1<<<(NN + 3) / 4, 256, 0, stream>>>(bufAh, bufB, offs_r, csr_r, dinv_r);
        k_stats<HH><<<256, dim3(HH, 256 / HH), 0, stream>>>(bufB, partial);
        k_finalize<HH><<<1, HH, 0, stream>>>(partial, g1 + r * HH, be1 + r * HH, ab);
        k_apply1<<<(NN * HH / 4 + 255) / 256, 256, 0, stream>>>(bufB, ab, bufBh);

        k_mm2<<<(NN + 255) / 256, 256, 0, stream>>>(bufBh, W2t + (size_t)r * HH * OO, bufCh);
        k_agg2<<<(NN + 7) / 8, 256, 0, stream>>>(bufCh, bufD, offs_r, csr_r, dinv_r);
        k_stats<OO><<<256, dim3(OO, 256 / OO), 0, stream>>>(bufD, partial);
        k_finalize<OO><<<1, OO, 0, stream>>>(partial, g2 + r * OO, be2 + r * OO, ab);
        k_apply<OO><<<(NN * OO / 4 + 255) / 256, 256, 0, stream>>>(bufD, ab);

        k_lsm<<<(BB + 7) / 8, dim3(32, 8), 0, stream>>>(bufD, batch, out, r);
    }
}

// Round 5
// 1009.348 us; speedup vs baseline: 2.4472x; 1.0811x over previous
//
#include <hip/hip_runtime.h>
#include <math.h>

#define NN 50000
#define EE 800000
#define RR 4
#define FF 256
#define HH 128
#define OO 32
#define BB 10000
#define EPSV 1e-5f

#define NSEG 64            // pass-A blocks per relation
#define CH   (EE / NSEG)   // 12500 edges per block
#define NBK  256           // node buckets
#define BNODE 196          // nodes per bucket (256*196 = 50176 >= NN)
#define SCAP 96            // per (block,bucket) segment cap; mean 48.8, +6.7 sigma

typedef __bf16 bf16_t;
typedef __attribute__((ext_vector_type(8))) bf16_t bf16x8;
typedef __attribute__((ext_vector_type(4))) float f32x4;

__device__ __forceinline__ unsigned short f2bf(float f) {
    unsigned int u = __float_as_uint(f);
    u += 0x7fff + ((u >> 16) & 1);
    return (unsigned short)(u >> 16);
}
__device__ __forceinline__ float bf2f(unsigned short s) {
    return __uint_as_float(((unsigned int)s) << 16);
}
__device__ __forceinline__ void load_lds16(const void* g, void* l) {
    __builtin_amdgcn_global_load_lds(
        (const __attribute__((address_space(1))) unsigned int*)g,
        (__attribute__((address_space(3))) unsigned int*)l, 16, 0, 0);
}

// ---------------- conversions ----------------

__global__ void k_cvt_feat(const float* __restrict__ in, ushort* __restrict__ out) {
    int idx = blockIdx.x * 256 + threadIdx.x;
    const float4* p = (const float4*)in + (size_t)idx * 2;
    float4 a = p[0], b = p[1];
    uint4 o;
    o.x = (unsigned)f2bf(a.x) | ((unsigned)f2bf(a.y) << 16);
    o.y = (unsigned)f2bf(a.z) | ((unsigned)f2bf(a.w) << 16);
    o.z = (unsigned)f2bf(b.x) | ((unsigned)f2bf(b.y) << 16);
    o.w = (unsigned)f2bf(b.z) | ((unsigned)f2bf(b.w) << 16);
    ((uint4*)out)[idx] = o;
}

__global__ void k_cvt_w1(const float* __restrict__ in, ushort* __restrict__ out) {
    int idx = blockIdx.x * 256 + threadIdx.x;
    if (idx >= RR * FF * HH) return;
    int r = idx >> 15, k = (idx >> 7) & 255, n = idx & 127;
    out[r * (HH * FF) + n * FF + k] = f2bf(in[idx]);
}

__global__ void k_cvt_w2(const float* __restrict__ in, ushort* __restrict__ out) {
    int idx = blockIdx.x * 256 + threadIdx.x;
    if (idx >= RR * HH * OO) return;
    int r = idx >> 12, k = (idx >> 5) & 127, n = idx & 31;
    out[r * (OO * HH) + n * HH + k] = f2bf(in[idx]);
}

// ---------------- CSR build ----------------

// Pass A: block-private chunk -> 256 block-private bucket segments (LDS cursors).
__global__ __launch_bounds__(256) void k_passA(const int* __restrict__ edges,
                                               uint2* __restrict__ seg,
                                               int* __restrict__ cnt) {
    int r = blockIdx.y, blk = blockIdx.x, t = threadIdx.x;
    __shared__ int lcur[NBK];
    lcur[t] = 0;
    __syncthreads();
    const int* srcp = edges + (size_t)r * 2 * EE + blk * CH;
    const int* dstp = srcp + EE;
    uint2* segbase = seg + (size_t)(r * NSEG + blk) * NBK * SCAP;
    for (int i = t; i < CH; i += 256) {
        int s = srcp[i], d = dstp[i];
        int b = d / BNODE;
        int pos = atomicAdd(&lcur[b], 1);
        if (pos < SCAP) segbase[b * SCAP + pos] = make_uint2((unsigned)s, (unsigned)d);
    }
    __syncthreads();
    cnt[(r * NSEG + blk) * NBK + t] = min(lcur[t], SCAP);
}

// bucket base offsets: exclusive prefix of per-bucket totals (256 / relation)
__global__ void k_bbase(const int* __restrict__ cnt, int* __restrict__ bbase,
                        int* __restrict__ offs) {
    int r = blockIdx.x, t = threadIdx.x;  // 256 threads
    int sum = 0;
    for (int s = 0; s < NSEG; ++s) sum += cnt[(r * NSEG + s) * NBK + t];
    __shared__ int sh[256];
    sh[t] = sum;
    __syncthreads();
    for (int off = 1; off < 256; off <<= 1) {
        int u = (t >= off) ? sh[t - off] : 0;
        __syncthreads();
        sh[t] += u;
        __syncthreads();
    }
    bbase[r * (NBK + 1) + t] = sh[t] - sum;
    if (t == 255) {
        bbase[r * (NBK + 1) + NBK] = sh[t];
        offs[r * (NN + 1) + NN] = sh[t];
    }
}

// Pass B: per (bucket, relation): LDS histogram + prefix -> offs/dinv (coalesced),
// then scatter srcs DIRECTLY into the bucket's contiguous global CSR span.
__global__ __launch_bounds__(256) void k_passB(const uint2* __restrict__ seg,
                                               const int* __restrict__ cnt,
                                               const int* __restrict__ bbase,
                                               int* __restrict__ csr,
                                               int* __restrict__ offs,
                                               float* __restrict__ dinv) {
    int b = blockIdx.x, r = blockIdx.y, t = threadIdx.x;
    __shared__ int ldeg[256];
    __shared__ int lcur[256];
    __shared__ int sh[256];
    __shared__ int scnt[NSEG];
    ldeg[t] = 0;
    if (t < NSEG) scnt[t] = cnt[(r * NSEG + t) * NBK + b];
    __syncthreads();
    int n0 = b * BNODE;
    const uint2* segb = seg + (size_t)(r * NSEG) * NBK * SCAP + (size_t)b * SCAP;
    // count
    for (int idx = t; idx < NSEG * SCAP; idx += 256) {
        int s = idx / SCAP, i = idx - s * SCAP;
        if (i < scnt[s])
            atomicAdd(&ldeg[(int)segb[(size_t)s * NBK * SCAP + i].y - n0], 1);
    }
    __syncthreads();
    int v = ldeg[t];
    sh[t] = v;
    __syncthreads();
    for (int off = 1; off < 256; off <<= 1) {
        int u = (t >= off) ? sh[t - off] : 0;
        __syncthreads();
        sh[t] += u;
        __syncthreads();
    }
    int ex = sh[t] - v;
    lcur[t] = ex;
    int gbase = bbase[r * (NBK + 1) + b];
    int n = n0 + t;
    if (t < BNODE && n < NN) {
        offs[r * (NN + 1) + n] = gbase + ex;
        dinv[r * NN + n] = rsqrtf((float)(v + 1));
    }
    __syncthreads();
    // scatter direct to global CSR span (single-owner block -> L2 write-combining)
    int* csrb = csr + (size_t)r * EE + gbase;
    for (int idx = t; idx < NSEG * SCAP; idx += 256) {
        int s = idx / SCAP, i = idx - s * SCAP;
        if (i < scnt[s]) {
            uint2 e = segb[(size_t)s * NBK * SCAP + i];
            int p = atomicAdd(&lcur[(int)e.y - n0], 1);
            csrb[p] = (int)e.x;
        }
    }
}

// ---------------- MFMA GEMM1: C[N][128] = A[N][256] x W1t[128][256]^T ----------------

__global__ __launch_bounds__(256) void k_mm1(const ushort* __restrict__ A,
                                             const ushort* __restrict__ Wt,
                                             ushort* __restrict__ C) {
    __shared__ __align__(16) ushort As[128 * 32];
    __shared__ __align__(16) ushort Bs[128 * 32];
    int tid = threadIdx.x;
    int lane = tid & 63, w = tid >> 6;
    int wm = w >> 1, wn = w & 1;
    int row0 = blockIdx.x * 128;
    int l15 = lane & 15, l4 = lane >> 4;

    f32x4 acc[4][4];
#pragma unroll
    for (int mf = 0; mf < 4; ++mf)
#pragma unroll
        for (int nf = 0; nf < 4; ++nf) acc[mf][nf] = (f32x4)0.f;

    for (int k0 = 0; k0 < FF; k0 += 32) {
#pragma unroll
        for (int i = 0; i < 2; ++i) {
            int chunk = i * 256 + tid;
            int ar = chunk >> 2, as_ = chunk & 3;
            int grow = row0 + ar; if (grow > NN - 1) grow = NN - 1;
            load_lds16(A + (size_t)grow * FF + k0 + as_ * 8,
                       As + (size_t)(i * 256 + w * 64) * 8);
        }
#pragma unroll
        for (int i = 0; i < 2; ++i) {
            int chunk = i * 256 + tid;
            int bn = chunk >> 2, slot = chunk & 3;
            uint4 v = *(const uint4*)(Wt + bn * FF + k0 + slot * 8);
            int sw = slot ^ ((bn >> 1) & 3);
            *(uint4*)(Bs + bn * 32 + sw * 8) = v;
        }
        __syncthreads();
        bf16x8 af[4], bfr[4];
#pragma unroll
        for (int mf = 0; mf < 4; ++mf) {
            int row = wm * 64 + mf * 16 + l15;
            af[mf] = *(const bf16x8*)(As + row * 32 + l4 * 8);
        }
#pragma unroll
        for (int nf = 0; nf < 4; ++nf) {
            int n = wn * 64 + nf * 16 + l15;
            int sw = l4 ^ ((n >> 1) & 3);
            bfr[nf] = *(const bf16x8*)(Bs + n * 32 + sw * 8);
        }
#pragma unroll
        for (int mf = 0; mf < 4; ++mf)
#pragma unroll
            for (int nf = 0; nf < 4; ++nf)
                acc[mf][nf] = __builtin_amdgcn_mfma_f32_16x16x32_bf16(af[mf], bfr[nf], acc[mf][nf], 0, 0, 0);
        __syncthreads();
    }
#pragma unroll
    for (int mf = 0; mf < 4; ++mf) {
#pragma unroll
        for (int nf = 0; nf < 4; ++nf) {
#pragma unroll
            for (int j = 0; j < 4; ++j) {
                int row = row0 + wm * 64 + mf * 16 + l4 * 4 + j;
                if (row < NN)
                    C[(size_t)row * HH + wn * 64 + nf * 16 + l15] = f2bf(acc[mf][nf][j]);
            }
        }
    }
}

// ---- MFMA GEMM2 (fused BN1-apply+ReLU on A): C[N][32] = relu(a*A+b)[N][128] x W2t^T ----

__global__ __launch_bounds__(256) void k_mm2(const float* __restrict__ A,
                                             const float* __restrict__ ab,
                                             const ushort* __restrict__ Wt,
                                             ushort* __restrict__ C) {
    __shared__ __align__(16) ushort As[256 * 32];
    __shared__ __align__(16) ushort Ws2[32 * 128];
    int tid = threadIdx.x;
    int lane = tid & 63, w = tid >> 6;
    int l15 = lane & 15, l4 = lane >> 4;
    int row0 = blockIdx.x * 256;

#pragma unroll
    for (int i = 0; i < 2; ++i) {
        int chunk = i * 256 + tid;
        int n = chunk >> 4, slot = chunk & 15;
        uint4 v = *(const uint4*)(Wt + n * HH + slot * 8);
        int sw = slot ^ (n & 7);
        *(uint4*)(Ws2 + n * HH + sw * 8) = v;
    }

    f32x4 acc[4][2];
#pragma unroll
    for (int mf = 0; mf < 4; ++mf)
#pragma unroll
        for (int nf = 0; nf < 2; ++nf) acc[mf][nf] = (f32x4)0.f;

    for (int k0 = 0; k0 < HH; k0 += 32) {
#pragma unroll
        for (int i = 0; i < 4; ++i) {
            int chunk = i * 256 + tid;
            int ar = chunk >> 2, cg = chunk & 3;
            int grow = row0 + ar; if (grow > NN - 1) grow = NN - 1;
            const float* ap = A + (size_t)grow * HH + k0 + cg * 8;
            float4 x0 = *(const float4*)ap;
            float4 x1 = *(const float4*)(ap + 4);
            const float* aa = ab + k0 + cg * 8;
            float4 a0 = *(const float4*)aa;
            float4 a1 = *(const float4*)(aa + 4);
            const float* bp = ab + HH + k0 + cg * 8;
            float4 b0 = *(const float4*)bp;
            float4 b1 = *(const float4*)(bp + 4);
            float y0 = fmaxf(a0.x * x0.x + b0.x, 0.f);
            float y1 = fmaxf(a0.y * x0.y + b0.y, 0.f);
            float y2 = fmaxf(a0.z * x0.z + b0.z, 0.f);
            float y3 = fmaxf(a0.w * x0.w + b0.w, 0.f);
            float y4 = fmaxf(a1.x * x1.x + b1.x, 0.f);
            float y5 = fmaxf(a1.y * x1.y + b1.y, 0.f);
            float y6 = fmaxf(a1.z * x1.z + b1.z, 0.f);
            float y7 = fmaxf(a1.w * x1.w + b1.w, 0.f);
            uint4 o;
            o.x = (unsigned)f2bf(y0) | ((unsigned)f2bf(y1) << 16);
            o.y = (unsigned)f2bf(y2) | ((unsigned)f2bf(y3) << 16);
            o.z = (unsigned)f2bf(y4) | ((unsigned)f2bf(y5) << 16);
            o.w = (unsigned)f2bf(y6) | ((unsigned)f2bf(y7) << 16);
            *(uint4*)(As + chunk * 8) = o;
        }
        __syncthreads();
        bf16x8 af[4], bfr[2];
#pragma unroll
        for (int mf = 0; mf < 4; ++mf)
            af[mf] = *(const bf16x8*)(As + (w * 64 + mf * 16 + l15) * 32 + l4 * 8);
#pragma unroll
        for (int nf = 0; nf < 2; ++nf) {
            int n = nf * 16 + l15;
            int slot = (k0 >> 3) + l4;
            int sw = slot ^ (n & 7);
            bfr[nf] = *(const bf16x8*)(Ws2 + n * HH + sw * 8);
        }
#pragma unroll
        for (int mf = 0; mf < 4; ++mf)
#pragma unroll
            for (int nf = 0; nf < 2; ++nf)
                acc[mf][nf] = __builtin_amdgcn_mfma_f32_16x16x32_bf16(af[mf], bfr[nf], acc[mf][nf], 0, 0, 0);
        __syncthreads();
    }
#pragma unroll
    for (int mf = 0; mf < 4; ++mf) {
#pragma unroll
        for (int nf = 0; nf < 2; ++nf) {
#pragma unroll
            for (int j = 0; j < 4; ++j) {
                int row = row0 + w * 64 + mf * 16 + l4 * 4 + j;
                if (row < NN)
                    C[(size_t)row * OO + nf * 16 + l15] = f2bf(acc[mf][nf][j]);
            }
        }
    }
}

// ---------------- aggregation (bf16 in, fp32 out) ----------------

__global__ void k_agg1(const ushort* __restrict__ X, float* __restrict__ Y,
                       const int* __restrict__ offs, const int* __restrict__ csr,
                       const float* __restrict__ dinv) {
    int tid = threadIdx.x;
    int wid = tid >> 6, lane = tid & 63;
    int n = blockIdx.x * 4 + wid;
    if (n >= NN) return;
    int c = lane * 2;
    float ax = 0.f, ay = 0.f;
    int s0 = offs[n], s1 = offs[n + 1];
    for (int e = s0; e < s1; ++e) {
        int s = csr[e];
        float wgt = dinv[s];
        unsigned v = *(const unsigned*)(X + (size_t)s * HH + c);
        ax += wgt * bf2f((ushort)(v & 0xffff));
        ay += wgt * bf2f((ushort)(v >> 16));
    }
    float dn = dinv[n];
    unsigned v = *(const unsigned*)(X + (size_t)n * HH + c);
    ax += dn * bf2f((ushort)(v & 0xffff));
    ay += dn * bf2f((ushort)(v >> 16));
    float2 o; o.x = ax * dn; o.y = ay * dn;
    *(float2*)(Y + (size_t)n * HH + c) = o;
}

__global__ void k_agg2(const ushort* __restrict__ X, float* __restrict__ Y,
                       const int* __restrict__ offs, const int* __restrict__ csr,
                       const float* __restrict__ dinv) {
    int tid = threadIdx.x;
    int wid = tid >> 6, lane = tid & 63;
    int sub = lane >> 5, col = lane & 31;
    int n = blockIdx.x * 8 + wid * 2 + sub;
    if (n >= NN) return;
    float acc = 0.f;
    int s0 = offs[n], s1 = offs[n + 1];
    for (int e = s0; e < s1; ++e) {
        int s = csr[e];
        acc += dinv[s] * bf2f(X[(size_t)s * OO + col]);
    }
    float dn = dinv[n];
    acc += dn * bf2f(X[(size_t)n * OO + col]);
    Y[(size_t)n * OO + col] = acc * dn;
}

// ---------------- batchnorm stats ----------------

template <int D>
__global__ void k_stats(const float* __restrict__ X, float* __restrict__ partial) {
    constexpr int BY = 256 / D;
    int c = threadIdx.x;
    int ty = threadIdx.y;
    float s = 0.f, ss = 0.f;
    for (int row = blockIdx.x * BY + ty; row < NN; row += gridDim.x * BY) {
        float v = X[(size_t)row * D + c];
        s += v; ss += v * v;
    }
    __shared__ float ls[BY][D];
    __shared__ float lss[BY][D];
    ls[ty][c] = s; lss[ty][c] = ss;
    __syncthreads();
    if (ty == 0) {
#pragma unroll
        for (int y = 1; y < BY; ++y) { s += ls[y][c]; ss += lss[y][c]; }
        partial[blockIdx.x * 2 * D + c] = s;
        partial[blockIdx.x * 2 * D + D + c] = ss;
    }
}

template <int D>
__global__ void k_finalize(const float* __restrict__ partial, const float* __restrict__ g,
                           const float* __restrict__ be, float* __restrict__ ab) {
    int c = threadIdx.x;
    float s = 0.f, ss = 0.f;
    for (int i = 0; i < 256; ++i) {
        s += partial[i * 2 * D + c];
        ss += partial[i * 2 * D + D + c];
    }
    float mean = s / (float)NN;
    float var = ss / (float)NN - mean * mean;
    float rstd = rsqrtf(var + EPSV);
    float a = g[c] * rstd;
    ab[c] = a;
    ab[D + c] = be[c] - mean * a;
}

// ---------------- gather + BN2-apply + ReLU + log_softmax ----------------

__global__ void k_lsm(const float* __restrict__ X, const float* __restrict__ ab,
                      const int* __restrict__ batch, float* __restrict__ out, int r) {
    int tx = threadIdx.x;  // 32 = OO
    int b = blockIdx.x * blockDim.y + threadIdx.y;
    if (b >= BB) return;
    int node = batch[b];
    float x = X[(size_t)node * OO + tx];
    float v = fmaxf(ab[tx] * x + ab[OO + tx], 0.f);
    float m = v;
#pragma unroll
    for (int off = 16; off; off >>= 1) m = fmaxf(m, __shfl_xor(m, off, 32));
    float e = expf(v - m);
    float sum = e;
#pragma unroll
    for (int off = 16; off; off >>= 1) sum += __shfl_xor(sum, off, 32);
    out[(size_t)b * (RR * OO) + r * OO + tx] = v - m - logf(sum);
}

// ---------------- host ----------------

extern "C" void kernel_launch(void* const* d_in, const int* in_sizes, int n_in,
                              void* d_out, int out_size, void* d_ws, size_t ws_size,
                              hipStream_t stream) {
    const float* features = (const float*)d_in[0];
    const int* edges = (const int*)d_in[1];
    const int* batch = (const int*)d_in[2];
    const float* W1 = (const float*)d_in[3];
    const float* g1 = (const float*)d_in[5];
    const float* be1 = (const float*)d_in[6];
    const float* W2 = (const float*)d_in[7];
    const float* g2 = (const float*)d_in[9];
    const float* be2 = (const float*)d_in[10];
    float* out = (float*)d_out;

    char* p = (char*)d_ws;
    auto carve = [&](size_t bytes) {
        void* q = (void*)p;
        p += (bytes + 255) & ~(size_t)255;
        return q;
    };
    ushort* Fbf = (ushort*)carve((size_t)NN * FF * 2);
    ushort* W1t = (ushort*)carve((size_t)RR * FF * HH * 2);
    ushort* W2t = (ushort*)carve((size_t)RR * HH * OO * 2);
    float* dinv = (float*)carve((size_t)RR * NN * 4);
    int* offs = (int*)carve((size_t)RR * (NN + 1) * 4);
    int* cnt = (int*)carve((size_t)RR * NSEG * NBK * 4);
    int* bbase = (int*)carve((size_t)RR * (NBK + 1) * 4);
    int* csr = (int*)carve((size_t)RR * EE * 4);
    ushort* bufAh = (ushort*)carve((size_t)NN * HH * 2);
    float* bufB = (float*)carve((size_t)NN * HH * 4);
    ushort* bufCh = (ushort*)carve((size_t)NN * OO * 2);
    float* bufD = (float*)carve((size_t)NN * OO * 4);
    float* partial = (float*)carve((size_t)256 * 2 * HH * 4);
    float* ab1 = (float*)carve((size_t)2 * HH * 4);
    float* ab2 = (float*)carve((size_t)2 * OO * 4);
    carve((size_t)3 << 20);  // pad so seg alias below fits
    // seg staging (RR*NSEG*NBK*SCAP*8B = 50.3 MB) aliases bufAh..pad
    // (12.8+25.6+3.2+6.4+0.26+~0+3.1 = 51.4 MB); dead before bufAh is first written.
    uint2* seg = (uint2*)bufAh;

    k_cvt_feat<<<NN * FF / 8 / 256, 256, 0, stream>>>(features, Fbf);
    k_cvt_w1<<<(RR * FF * HH + 255) / 256, 256, 0, stream>>>(W1, W1t);
    k_cvt_w2<<<(RR * HH * OO + 255) / 256, 256, 0, stream>>>(W2, W2t);

    k_passA<<<dim3(NSEG, RR), 256, 0, stream>>>(edges, seg, cnt);
    k_bbase<<<RR, 256, 0, stream>>>(cnt, bbase, offs);
    k_passB<<<dim3(NBK, RR), 256, 0, stream>>>(seg, cnt, bbase, csr, offs, dinv);

    for (int r = 0; r < RR; ++r) {
        const int* offs_r = offs + r * (NN + 1);
        const int* csr_r = csr + (size_t)r * EE;
        const float* dinv_r = dinv + (size_t)r * NN;

        k_mm1<<<(NN + 127) / 128, 256, 0, stream>>>(Fbf, W1t + (size_t)r * FF * HH, bufAh);
        k_agg1<<<(NN + 3) / 4, 256, 0, stream>>>(bufAh, bufB, offs_r, csr_r, dinv_r);
        k_stats<HH><<<256, dim3(HH, 256 / HH), 0, stream>>>(bufB, partial);
        k_finalize<HH><<<1, HH, 0, stream>>>(partial, g1 + r * HH, be1 + r * HH, ab1);

        k_mm2<<<(NN + 255) / 256, 256, 0, stream>>>(bufB, ab1, W2t + (size_t)r * HH * OO, bufCh);
        k_agg2<<<(NN + 7) / 8, 256, 0, stream>>>(bufCh, bufD, offs_r, csr_r, dinv_r);
        k_stats<OO><<<256, dim3(OO, 256 / OO), 0, stream>>>(bufD, partial);
        k_finalize<OO><<<1, OO, 0, stream>>>(partial, g2 + r * OO, be2 + r * OO, ab2);

        k_lsm<<<(BB + 7) / 8, dim3(32, 8), 0, stream>>>(bufD, ab2, batch, out, r);
    }
}

// Round 6
// 767.843 us; speedup vs baseline: 3.2169x; 1.3145x over previous
//
#include <hip/hip_runtime.h>
#include <math.h>

#define NN 50000
#define EE 800000
#define RR 4
#define FF 256
#define HH 128
#define OO 32
#define BB 10000
#define EPSV 1e-5f

#define NSEG 64            // pass-A blocks per relation
#define CH   (EE / NSEG)   // 12500 edges per block
#define NBK  256           // node buckets
#define BNODE 196          // nodes per bucket (256*196 = 50176 >= NN)
#define SCAP 96            // per (block,bucket) segment cap; mean 48.8, +6.7 sigma

typedef __bf16 bf16_t;
typedef __attribute__((ext_vector_type(8))) bf16_t bf16x8;
typedef __attribute__((ext_vector_type(4))) float f32x4;

__device__ __forceinline__ unsigned short f2bf(float f) {
    unsigned int u = __float_as_uint(f);
    u += 0x7fff + ((u >> 16) & 1);
    return (unsigned short)(u >> 16);
}
__device__ __forceinline__ float bf2f(unsigned short s) {
    return __uint_as_float(((unsigned int)s) << 16);
}
__device__ __forceinline__ void load_lds16(const void* g, void* l) {
    __builtin_amdgcn_global_load_lds(
        (const __attribute__((address_space(1))) unsigned int*)g,
        (__attribute__((address_space(3))) unsigned int*)l, 16, 0, 0);
}

// ---------------- conversions ----------------

__global__ void k_cvt_feat(const float* __restrict__ in, ushort* __restrict__ out) {
    int idx = blockIdx.x * 256 + threadIdx.x;
    const float4* p = (const float4*)in + (size_t)idx * 2;
    float4 a = p[0], b = p[1];
    uint4 o;
    o.x = (unsigned)f2bf(a.x) | ((unsigned)f2bf(a.y) << 16);
    o.y = (unsigned)f2bf(a.z) | ((unsigned)f2bf(a.w) << 16);
    o.z = (unsigned)f2bf(b.x) | ((unsigned)f2bf(b.y) << 16);
    o.w = (unsigned)f2bf(b.z) | ((unsigned)f2bf(b.w) << 16);
    ((uint4*)out)[idx] = o;
}

__global__ void k_cvt_w1(const float* __restrict__ in, ushort* __restrict__ out) {
    int idx = blockIdx.x * 256 + threadIdx.x;
    if (idx >= RR * FF * HH) return;
    int r = idx >> 15, k = (idx >> 7) & 255, n = idx & 127;
    out[r * (HH * FF) + n * FF + k] = f2bf(in[idx]);
}

__global__ void k_cvt_w2(const float* __restrict__ in, ushort* __restrict__ out) {
    int idx = blockIdx.x * 256 + threadIdx.x;
    if (idx >= RR * HH * OO) return;
    int r = idx >> 12, k = (idx >> 5) & 127, n = idx & 31;
    out[r * (OO * HH) + n * HH + k] = f2bf(in[idx]);
}

// ---------------- CSR build ----------------

// Pass A: block-private chunk -> 256 block-private bucket segments (LDS cursors).
// Record: src (16b, NN<65536) | dloc (dst - bucket_base, 8b) << 16.
__global__ __launch_bounds__(256) void k_passA(const int* __restrict__ edges,
                                               uint* __restrict__ seg,
                                               int* __restrict__ cnt) {
    int r = blockIdx.y, blk = blockIdx.x, t = threadIdx.x;
    __shared__ int lcur[NBK];
    lcur[t] = 0;
    __syncthreads();
    const int* srcp = edges + (size_t)r * 2 * EE + blk * CH;
    const int* dstp = srcp + EE;
    uint* segbase = seg + (size_t)(r * NSEG + blk) * NBK * SCAP;
    for (int i = t; i < CH; i += 256) {
        int s = srcp[i], d = dstp[i];
        int b = d / BNODE;
        int dloc = d - b * BNODE;
        int pos = atomicAdd(&lcur[b], 1);
        if (pos < SCAP) segbase[b * SCAP + pos] = (uint)s | ((uint)dloc << 16);
    }
    __syncthreads();
    cnt[(r * NSEG + blk) * NBK + t] = min(lcur[t], SCAP);
}

// bucket base offsets: exclusive prefix of per-bucket totals (256 / relation)
__global__ void k_bbase(const int* __restrict__ cnt, int* __restrict__ bbase,
                        int* __restrict__ offs) {
    int r = blockIdx.x, t = threadIdx.x;
    int sum = 0;
    for (int s = 0; s < NSEG; ++s) sum += cnt[(r * NSEG + s) * NBK + t];
    __shared__ int sh[256];
    sh[t] = sum;
    __syncthreads();
    for (int off = 1; off < 256; off <<= 1) {
        int u = (t >= off) ? sh[t - off] : 0;
        __syncthreads();
        sh[t] += u;
        __syncthreads();
    }
    bbase[r * (NBK + 1) + t] = sh[t] - sum;
    if (t == 255) {
        bbase[r * (NBK + 1) + NBK] = sh[t];
        offs[r * (NN + 1) + NN] = sh[t];
    }
}

// Pass B: per (bucket, relation): LDS histogram + prefix -> offs/dinv (coalesced),
// then scatter src ids DIRECTLY into the bucket's contiguous global CSR span.
__global__ __launch_bounds__(256) void k_passB(const uint* __restrict__ seg,
                                               const int* __restrict__ cnt,
                                               const int* __restrict__ bbase,
                                               ushort* __restrict__ csr,
                                               int* __restrict__ offs,
                                               float* __restrict__ dinv) {
    int b = blockIdx.x, r = blockIdx.y, t = threadIdx.x;
    __shared__ int ldeg[256];
    __shared__ int lcur[256];
    __shared__ int sh[256];
    __shared__ int scnt[NSEG];
    ldeg[t] = 0;
    if (t < NSEG) scnt[t] = cnt[(r * NSEG + t) * NBK + b];
    __syncthreads();
    const uint* segb = seg + (size_t)(r * NSEG) * NBK * SCAP + (size_t)b * SCAP;
    // count
    for (int idx = t; idx < NSEG * SCAP; idx += 256) {
        int s = idx / SCAP, i = idx - s * SCAP;
        if (i < scnt[s])
            atomicAdd(&ldeg[segb[(size_t)s * NBK * SCAP + i] >> 16], 1);
    }
    __syncthreads();
    int v = ldeg[t];
    sh[t] = v;
    __syncthreads();
    for (int off = 1; off < 256; off <<= 1) {
        int u = (t >= off) ? sh[t - off] : 0;
        __syncthreads();
        sh[t] += u;
        __syncthreads();
    }
    int ex = sh[t] - v;
    lcur[t] = ex;
    int gbase = bbase[r * (NBK + 1) + b];
    int n0 = b * BNODE;
    int n = n0 + t;
    if (t < BNODE && n < NN) {
        offs[r * (NN + 1) + n] = gbase + ex;
        dinv[r * NN + n] = rsqrtf((float)(v + 1));
    }
    __syncthreads();
    // scatter direct to global CSR span (single-owner block -> L2 write-combining)
    ushort* csrb = csr + (size_t)r * EE + gbase;
    for (int idx = t; idx < NSEG * SCAP; idx += 256) {
        int s = idx / SCAP, i = idx - s * SCAP;
        if (i < scnt[s]) {
            uint e = segb[(size_t)s * NBK * SCAP + i];
            int p = atomicAdd(&lcur[e >> 16], 1);
            csrb[p] = (ushort)(e & 0xffffu);
        }
    }
}

// ---------------- MFMA GEMM1: C[N][128] = A[N][256] x W1t[128][256]^T ----------------

__global__ __launch_bounds__(256) void k_mm1(const ushort* __restrict__ A,
                                             const ushort* __restrict__ Wt,
                                             ushort* __restrict__ C) {
    __shared__ __align__(16) ushort As[128 * 32];
    __shared__ __align__(16) ushort Bs[128 * 32];
    int tid = threadIdx.x;
    int lane = tid & 63, w = tid >> 6;
    int wm = w >> 1, wn = w & 1;
    int row0 = blockIdx.x * 128;
    int l15 = lane & 15, l4 = lane >> 4;

    f32x4 acc[4][4];
#pragma unroll
    for (int mf = 0; mf < 4; ++mf)
#pragma unroll
        for (int nf = 0; nf < 4; ++nf) acc[mf][nf] = (f32x4)0.f;

    for (int k0 = 0; k0 < FF; k0 += 32) {
#pragma unroll
        for (int i = 0; i < 2; ++i) {
            int chunk = i * 256 + tid;
            int ar = chunk >> 2, as_ = chunk & 3;
            int grow = row0 + ar; if (grow > NN - 1) grow = NN - 1;
            load_lds16(A + (size_t)grow * FF + k0 + as_ * 8,
                       As + (size_t)(i * 256 + w * 64) * 8);
        }
#pragma unroll
        for (int i = 0; i < 2; ++i) {
            int chunk = i * 256 + tid;
            int bn = chunk >> 2, slot = chunk & 3;
            uint4 v = *(const uint4*)(Wt + bn * FF + k0 + slot * 8);
            int sw = slot ^ ((bn >> 1) & 3);
            *(uint4*)(Bs + bn * 32 + sw * 8) = v;
        }
        __syncthreads();
        bf16x8 af[4], bfr[4];
#pragma unroll
        for (int mf = 0; mf < 4; ++mf) {
            int row = wm * 64 + mf * 16 + l15;
            af[mf] = *(const bf16x8*)(As + row * 32 + l4 * 8);
        }
#pragma unroll
        for (int nf = 0; nf < 4; ++nf) {
            int n = wn * 64 + nf * 16 + l15;
            int sw = l4 ^ ((n >> 1) & 3);
            bfr[nf] = *(const bf16x8*)(Bs + n * 32 + sw * 8);
        }
#pragma unroll
        for (int mf = 0; mf < 4; ++mf)
#pragma unroll
            for (int nf = 0; nf < 4; ++nf)
                acc[mf][nf] = __builtin_amdgcn_mfma_f32_16x16x32_bf16(af[mf], bfr[nf], acc[mf][nf], 0, 0, 0);
        __syncthreads();
    }
#pragma unroll
    for (int mf = 0; mf < 4; ++mf) {
#pragma unroll
        for (int nf = 0; nf < 4; ++nf) {
#pragma unroll
            for (int j = 0; j < 4; ++j) {
                int row = row0 + wm * 64 + mf * 16 + l4 * 4 + j;
                if (row < NN)
                    C[(size_t)row * HH + wn * 64 + nf * 16 + l15] = f2bf(acc[mf][nf][j]);
            }
        }
    }
}

// ---- MFMA GEMM2 (fused BN1-apply+ReLU on A): C[N][32] = relu(a*A+b)[N][128] x W2t^T ----

__global__ __launch_bounds__(256) void k_mm2(const float* __restrict__ A,
                                             const float* __restrict__ ab,
                                             const ushort* __restrict__ Wt,
                                             ushort* __restrict__ C) {
    __shared__ __align__(16) ushort As[256 * 32];
    __shared__ __align__(16) ushort Ws2[32 * 128];
    int tid = threadIdx.x;
    int lane = tid & 63, w = tid >> 6;
    int l15 = lane & 15, l4 = lane >> 4;
    int row0 = blockIdx.x * 256;

#pragma unroll
    for (int i = 0; i < 2; ++i) {
        int chunk = i * 256 + tid;
        int n = chunk >> 4, slot = chunk & 15;
        uint4 v = *(const uint4*)(Wt + n * HH + slot * 8);
        int sw = slot ^ (n & 7);
        *(uint4*)(Ws2 + n * HH + sw * 8) = v;
    }

    f32x4 acc[4][2];
#pragma unroll
    for (int mf = 0; mf < 4; ++mf)
#pragma unroll
        for (int nf = 0; nf < 2; ++nf) acc[mf][nf] = (f32x4)0.f;

    for (int k0 = 0; k0 < HH; k0 += 32) {
#pragma unroll
        for (int i = 0; i < 4; ++i) {
            int chunk = i * 256 + tid;
            int ar = chunk >> 2, cg = chunk & 3;
            int grow = row0 + ar; if (grow > NN - 1) grow = NN - 1;
            const float* ap = A + (size_t)grow * HH + k0 + cg * 8;
            float4 x0 = *(const float4*)ap;
            float4 x1 = *(const float4*)(ap + 4);
            const float* aa = ab + k0 + cg * 8;
            float4 a0 = *(const float4*)aa;
            float4 a1 = *(const float4*)(aa + 4);
            const float* bp = ab + HH + k0 + cg * 8;
            float4 b0 = *(const float4*)bp;
            float4 b1 = *(const float4*)(bp + 4);
            float y0 = fmaxf(a0.x * x0.x + b0.x, 0.f);
            float y1 = fmaxf(a0.y * x0.y + b0.y, 0.f);
            float y2 = fmaxf(a0.z * x0.z + b0.z, 0.f);
            float y3 = fmaxf(a0.w * x0.w + b0.w, 0.f);
            float y4 = fmaxf(a1.x * x1.x + b1.x, 0.f);
            float y5 = fmaxf(a1.y * x1.y + b1.y, 0.f);
            float y6 = fmaxf(a1.z * x1.z + b1.z, 0.f);
            float y7 = fmaxf(a1.w * x1.w + b1.w, 0.f);
            uint4 o;
            o.x = (unsigned)f2bf(y0) | ((unsigned)f2bf(y1) << 16);
            o.y = (unsigned)f2bf(y2) | ((unsigned)f2bf(y3) << 16);
            o.z = (unsigned)f2bf(y4) | ((unsigned)f2bf(y5) << 16);
            o.w = (unsigned)f2bf(y6) | ((unsigned)f2bf(y7) << 16);
            *(uint4*)(As + chunk * 8) = o;
        }
        __syncthreads();
        bf16x8 af[4], bfr[2];
#pragma unroll
        for (int mf = 0; mf < 4; ++mf)
            af[mf] = *(const bf16x8*)(As + (w * 64 + mf * 16 + l15) * 32 + l4 * 8);
#pragma unroll
        for (int nf = 0; nf < 2; ++nf) {
            int n = nf * 16 + l15;
            int slot = (k0 >> 3) + l4;
            int sw = slot ^ (n & 7);
            bfr[nf] = *(const bf16x8*)(Ws2 + n * HH + sw * 8);
        }
#pragma unroll
        for (int mf = 0; mf < 4; ++mf)
#pragma unroll
            for (int nf = 0; nf < 2; ++nf)
                acc[mf][nf] = __builtin_amdgcn_mfma_f32_16x16x32_bf16(af[mf], bfr[nf], acc[mf][nf], 0, 0, 0);
        __syncthreads();
    }
#pragma unroll
    for (int mf = 0; mf < 4; ++mf) {
#pragma unroll
        for (int nf = 0; nf < 2; ++nf) {
#pragma unroll
            for (int j = 0; j < 4; ++j) {
                int row = row0 + w * 64 + mf * 16 + l4 * 4 + j;
                if (row < NN)
                    C[(size_t)row * OO + nf * 16 + l15] = f2bf(acc[mf][nf][j]);
            }
        }
    }
}

// ---------------- aggregation (bf16 in, fp32 out), 4x MLP unroll ----------------

__global__ void k_agg1(const ushort* __restrict__ X, float* __restrict__ Y,
                       const int* __restrict__ offs, const ushort* __restrict__ csr,
                       const float* __restrict__ dinv) {
    int tid = threadIdx.x;
    int wid = tid >> 6, lane = tid & 63;
    int n = blockIdx.x * 4 + wid;
    if (n >= NN) return;
    const uint* Xu = (const uint*)X;  // row stride 64 uints (128 bf16)
    float ax = 0.f, ay = 0.f;
    int e = offs[n], s1 = offs[n + 1];
    for (; e + 4 <= s1; e += 4) {
        int sa = csr[e], sb = csr[e + 1], sc = csr[e + 2], sd = csr[e + 3];
        uint va = Xu[sa * 64 + lane];
        uint vb = Xu[sb * 64 + lane];
        uint vc = Xu[sc * 64 + lane];
        uint vd = Xu[sd * 64 + lane];
        float wa = dinv[sa], wb = dinv[sb], wc = dinv[sc], wd = dinv[sd];
        ax += wa * bf2f((ushort)(va & 0xffff)); ay += wa * bf2f((ushort)(va >> 16));
        ax += wb * bf2f((ushort)(vb & 0xffff)); ay += wb * bf2f((ushort)(vb >> 16));
        ax += wc * bf2f((ushort)(vc & 0xffff)); ay += wc * bf2f((ushort)(vc >> 16));
        ax += wd * bf2f((ushort)(vd & 0xffff)); ay += wd * bf2f((ushort)(vd >> 16));
    }
    for (; e < s1; ++e) {
        int s = csr[e];
        float w = dinv[s];
        uint v = Xu[s * 64 + lane];
        ax += w * bf2f((ushort)(v & 0xffff)); ay += w * bf2f((ushort)(v >> 16));
    }
    float dn = dinv[n];
    uint v = Xu[n * 64 + lane];
    ax += dn * bf2f((ushort)(v & 0xffff));
    ay += dn * bf2f((ushort)(v >> 16));
    float2 o; o.x = ax * dn; o.y = ay * dn;
    *(float2*)(Y + (size_t)n * HH + lane * 2) = o;
}

__global__ void k_agg2(const ushort* __restrict__ X, float* __restrict__ Y,
                       const int* __restrict__ offs, const ushort* __restrict__ csr,
                       const float* __restrict__ dinv) {
    int tid = threadIdx.x;
    int wid = tid >> 6, lane = tid & 63;
    int sub = lane >> 5, col = lane & 31;
    int n = blockIdx.x * 8 + wid * 2 + sub;
    if (n >= NN) return;
    float acc = 0.f;
    int e = offs[n], s1 = offs[n + 1];
    for (; e + 4 <= s1; e += 4) {
        int sa = csr[e], sb = csr[e + 1], sc = csr[e + 2], sd = csr[e + 3];
        float xa = bf2f(X[sa * OO + col]);
        float xb = bf2f(X[sb * OO + col]);
        float xc = bf2f(X[sc * OO + col]);
        float xd = bf2f(X[sd * OO + col]);
        acc += dinv[sa] * xa + dinv[sb] * xb + dinv[sc] * xc + dinv[sd] * xd;
    }
    for (; e < s1; ++e) {
        int s = csr[e];
        acc += dinv[s] * bf2f(X[s * OO + col]);
    }
    float dn = dinv[n];
    acc += dn * bf2f(X[n * OO + col]);
    Y[(size_t)n * OO + col] = acc * dn;
}

// ---------------- batchnorm stats ----------------

template <int D>
__global__ void k_stats(const float* __restrict__ X, float* __restrict__ partial) {
    constexpr int BY = 256 / D;
    int c = threadIdx.x;
    int ty = threadIdx.y;
    float s = 0.f, ss = 0.f;
    for (int row = blockIdx.x * BY + ty; row < NN; row += gridDim.x * BY) {
        float v = X[(size_t)row * D + c];
        s += v; ss += v * v;
    }
    __shared__ float ls[BY][D];
    __shared__ float lss[BY][D];
    ls[ty][c] = s; lss[ty][c] = ss;
    __syncthreads();
    if (ty == 0) {
#pragma unroll
        for (int y = 1; y < BY; ++y) { s += ls[y][c]; ss += lss[y][c]; }
        partial[blockIdx.x * 2 * D + c] = s;
        partial[blockIdx.x * 2 * D + D + c] = ss;
    }
}

template <int D>
__global__ void k_finalize(const float* __restrict__ partial, const float* __restrict__ g,
                           const float* __restrict__ be, float* __restrict__ ab) {
    int c = threadIdx.x;
    float s = 0.f, ss = 0.f;
    for (int i = 0; i < 256; ++i) {
        s += partial[i * 2 * D + c];
        ss += partial[i * 2 * D + D + c];
    }
    float mean = s / (float)NN;
    float var = ss / (float)NN - mean * mean;
    float rstd = rsqrtf(var + EPSV);
    float a = g[c] * rstd;
    ab[c] = a;
    ab[D + c] = be[c] - mean * a;
}

// ---------------- gather + BN2-apply + ReLU + log_softmax ----------------

__global__ void k_lsm(const float* __restrict__ X, const float* __restrict__ ab,
                      const int* __restrict__ batch, float* __restrict__ out, int r) {
    int tx = threadIdx.x;  // 32 = OO
    int b = blockIdx.x * blockDim.y + threadIdx.y;
    if (b >= BB) return;
    int node = batch[b];
    float x = X[(size_t)node * OO + tx];
    float v = fmaxf(ab[tx] * x + ab[OO + tx], 0.f);
    float m = v;
#pragma unroll
    for (int off = 16; off; off >>= 1) m = fmaxf(m, __shfl_xor(m, off, 32));
    float e = expf(v - m);
    float sum = e;
#pragma unroll
    for (int off = 16; off; off >>= 1) sum += __shfl_xor(sum, off, 32);
    out[(size_t)b * (RR * OO) + r * OO + tx] = v - m - logf(sum);
}

// ---------------- host ----------------

extern "C" void kernel_launch(void* const* d_in, const int* in_sizes, int n_in,
                              void* d_out, int out_size, void* d_ws, size_t ws_size,
                              hipStream_t stream) {
    const float* features = (const float*)d_in[0];
    const int* edges = (const int*)d_in[1];
    const int* batch = (const int*)d_in[2];
    const float* W1 = (const float*)d_in[3];
    const float* g1 = (const float*)d_in[5];
    const float* be1 = (const float*)d_in[6];
    const float* W2 = (const float*)d_in[7];
    const float* g2 = (const float*)d_in[9];
    const float* be2 = (const float*)d_in[10];
    float* out = (float*)d_out;

    char* p = (char*)d_ws;
    auto carve = [&](size_t bytes) {
        void* q = (void*)p;
        p += (bytes + 255) & ~(size_t)255;
        return q;
    };
    ushort* Fbf = (ushort*)carve((size_t)NN * FF * 2);
    ushort* W1t = (ushort*)carve((size_t)RR * FF * HH * 2);
    ushort* W2t = (ushort*)carve((size_t)RR * HH * OO * 2);
    float* dinv = (float*)carve((size_t)RR * NN * 4);
    int* offs = (int*)carve((size_t)RR * (NN + 1) * 4);
    int* cnt = (int*)carve((size_t)RR * NSEG * NBK * 4);
    int* bbase = (int*)carve((size_t)RR * (NBK + 1) * 4);
    ushort* csr = (ushort*)carve((size_t)RR * EE * 2);
    ushort* bufAh = (ushort*)carve((size_t)NN * HH * 2);
    float* bufB = (float*)carve((size_t)NN * HH * 4);
    ushort* bufCh = (ushort*)carve((size_t)NN * OO * 2);
    float* bufD = (float*)carve((size_t)NN * OO * 4);
    float* partial = (float*)carve((size_t)256 * 2 * HH * 4);
    float* ab1 = (float*)carve((size_t)2 * HH * 4);
    float* ab2 = (float*)carve((size_t)2 * OO * 4);
    // seg staging (RR*NSEG*NBK*SCAP*4B = 25.2 MB) aliases bufAh+bufB (38.4 MB);
    // dead before bufAh is first written (mm1 runs after passB in-stream).
    uint* seg = (uint*)bufAh;

    k_cvt_feat<<<NN * FF / 8 / 256, 256, 0, stream>>>(features, Fbf);
    k_cvt_w1<<<(RR * FF * HH + 255) / 256, 256, 0, stream>>>(W1, W1t);
    k_cvt_w2<<<(RR * HH * OO + 255) / 256, 256, 0, stream>>>(W2, W2t);

    k_passA<<<dim3(NSEG, RR), 256, 0, stream>>>(edges, seg, cnt);
    k_bbase<<<RR, 256, 0, stream>>>(cnt, bbase, offs);
    k_passB<<<dim3(NBK, RR), 256, 0, stream>>>(seg, cnt, bbase, csr, offs, dinv);

    for (int r = 0; r < RR; ++r) {
        const int* offs_r = offs + r * (NN + 1);
        const ushort* csr_r = csr + (size_t)r * EE;
        const float* dinv_r = dinv + (size_t)r * NN;

        k_mm1<<<(NN + 127) / 128, 256, 0, stream>>>(Fbf, W1t + (size_t)r * FF * HH, bufAh);
        k_agg1<<<(NN + 3) / 4, 256, 0, stream>>>(bufAh, bufB, offs_r, csr_r, dinv_r);
        k_stats<HH><<<256, dim3(HH, 256 / HH), 0, stream>>>(bufB, partial);
        k_finalize<HH><<<1, HH, 0, stream>>>(partial, g1 + r * HH, be1 + r * HH, ab1);

        k_mm2<<<(NN + 255) / 256, 256, 0, stream>>>(bufB, ab1, W2t + (size_t)r * HH * OO, bufCh);
        k_agg2<<<(NN + 7) / 8, 256, 0, stream>>>(bufCh, bufD, offs_r, csr_r, dinv_r);
        k_stats<OO><<<256, dim3(OO, 256 / OO), 0, stream>>>(bufD, partial);
        k_finalize<OO><<<1, OO, 0, stream>>>(partial, g2 + r * OO, be2 + r * OO, ab2);

        k_lsm<<<(BB + 7) / 8, dim3(32, 8), 0, stream>>>(bufD, ab2, batch, out, r);
    }
}

// Round 7
// 636.509 us; speedup vs baseline: 3.8806x; 1.2063x over previous
//
#include <hip/hip_runtime.h>
#include <math.h>

#define NN 50000
#define EE 800000
#define RR 4
#define FF 256
#define HH 128
#define OO 32
#define BB 10000
#define EPSV 1e-5f
#define PAIR 2

#define NSEG 256           // pass-A blocks per relation
#define CH   (EE / NSEG)   // 3125 edges per block
#define NBK  256           // node buckets
#define BNODE 196          // nodes per bucket (256*196 = 50176 >= NN)
#define SCAP 36            // per (block,bucket) cap; mean 12.2, ~ +7 sigma

typedef __bf16 bf16_t;
typedef __attribute__((ext_vector_type(8))) bf16_t bf16x8;
typedef __attribute__((ext_vector_type(4))) float f32x4;

__device__ __forceinline__ unsigned short f2bf(float f) {
    unsigned int u = __float_as_uint(f);
    u += 0x7fff + ((u >> 16) & 1);
    return (unsigned short)(u >> 16);
}
__device__ __forceinline__ float bf2f(unsigned short s) {
    return __uint_as_float(((unsigned int)s) << 16);
}
__device__ __forceinline__ void load_lds16(const void* g, void* l) {
    __builtin_amdgcn_global_load_lds(
        (const __attribute__((address_space(1))) unsigned int*)g,
        (__attribute__((address_space(3))) unsigned int*)l, 16, 0, 0);
}

// ---------------- conversions ----------------

__global__ void k_cvt_feat(const float* __restrict__ in, ushort* __restrict__ out) {
    int idx = blockIdx.x * 256 + threadIdx.x;
    const float4* p = (const float4*)in + (size_t)idx * 2;
    float4 a = p[0], b = p[1];
    uint4 o;
    o.x = (unsigned)f2bf(a.x) | ((unsigned)f2bf(a.y) << 16);
    o.y = (unsigned)f2bf(a.z) | ((unsigned)f2bf(a.w) << 16);
    o.z = (unsigned)f2bf(b.x) | ((unsigned)f2bf(b.y) << 16);
    o.w = (unsigned)f2bf(b.z) | ((unsigned)f2bf(b.w) << 16);
    ((uint4*)out)[idx] = o;
}

__global__ void k_cvt_w(const float* __restrict__ W1, const float* __restrict__ W2,
                        ushort* __restrict__ W1t, ushort* __restrict__ W2t) {
    int idx = blockIdx.x * 256 + threadIdx.x;  // 131072 threads
    if (idx < RR * FF * HH) {
        int r = idx >> 15, k = (idx >> 7) & 255, n = idx & 127;
        W1t[r * (HH * FF) + n * FF + k] = f2bf(W1[idx]);
    }
    if (idx < RR * HH * OO) {
        int r = idx >> 12, k = (idx >> 5) & 127, n = idx & 31;
        W2t[r * (OO * HH) + n * HH + k] = f2bf(W2[idx]);
    }
}

// ---------------- CSR build ----------------

// Pass A: block-private chunk -> 256 block-private bucket segments (LDS cursors).
// Record: src (16b) | dloc (dst - bucket_base) << 16.
__global__ __launch_bounds__(256) void k_passA(const int* __restrict__ edges,
                                               uint* __restrict__ seg,
                                               int* __restrict__ cnt) {
    int r = blockIdx.y, blk = blockIdx.x, t = threadIdx.x;
    __shared__ int lcur[NBK];
    lcur[t] = 0;
    __syncthreads();
    const int* srcp = edges + (size_t)r * 2 * EE + blk * CH;
    const int* dstp = srcp + EE;
    uint* segbase = seg + (size_t)(r * NSEG + blk) * NBK * SCAP;
    for (int i = t; i < CH; i += 256) {
        int s = srcp[i], d = dstp[i];
        int b = d / BNODE;
        int dloc = d - b * BNODE;
        int pos = atomicAdd(&lcur[b], 1);
        if (pos < SCAP) segbase[b * SCAP + pos] = (uint)s | ((uint)dloc << 16);
    }
    __syncthreads();
    cnt[(r * NSEG + blk) * NBK + t] = min(lcur[t], SCAP);
}

__global__ void k_bbase(const int* __restrict__ cnt, int* __restrict__ bbase,
                        int* __restrict__ offs) {
    int r = blockIdx.x, t = threadIdx.x;
    int sum = 0;
    for (int s = 0; s < NSEG; ++s) sum += cnt[(r * NSEG + s) * NBK + t];
    __shared__ int sh[256];
    sh[t] = sum;
    __syncthreads();
    for (int off = 1; off < 256; off <<= 1) {
        int u = (t >= off) ? sh[t - off] : 0;
        __syncthreads();
        sh[t] += u;
        __syncthreads();
    }
    bbase[r * (NBK + 1) + t] = sh[t] - sum;
    if (t == 255) {
        bbase[r * (NBK + 1) + NBK] = sh[t];
        offs[r * (NN + 1) + NN] = sh[t];
    }
}

// Pass B: per (bucket, relation): LDS histogram + prefix -> offs/dinv, then
// scatter src ids directly into the bucket's contiguous global CSR span.
__global__ __launch_bounds__(256) void k_passB(const uint* __restrict__ seg,
                                               const int* __restrict__ cnt,
                                               const int* __restrict__ bbase,
                                               ushort* __restrict__ csr,
                                               int* __restrict__ offs,
                                               float* __restrict__ dinv) {
    int b = blockIdx.x, r = blockIdx.y, t = threadIdx.x;
    __shared__ int ldeg[256];
    __shared__ int lcur[256];
    __shared__ int sh[256];
    __shared__ int scnt[NSEG];
    ldeg[t] = 0;
    scnt[t] = cnt[(r * NSEG + t) * NBK + b];
    __syncthreads();
    const uint* segb = seg + (size_t)(r * NSEG) * NBK * SCAP + (size_t)b * SCAP;
    for (int idx = t; idx < NSEG * SCAP; idx += 256) {
        int s = idx / SCAP, i = idx - s * SCAP;
        if (i < scnt[s])
            atomicAdd(&ldeg[segb[(size_t)s * NBK * SCAP + i] >> 16], 1);
    }
    __syncthreads();
    int v = ldeg[t];
    sh[t] = v;
    __syncthreads();
    for (int off = 1; off < 256; off <<= 1) {
        int u = (t >= off) ? sh[t - off] : 0;
        __syncthreads();
        sh[t] += u;
        __syncthreads();
    }
    int ex = sh[t] - v;
    lcur[t] = ex;
    int gbase = bbase[r * (NBK + 1) + b];
    int n0 = b * BNODE;
    int n = n0 + t;
    if (t < BNODE && n < NN) {
        offs[r * (NN + 1) + n] = gbase + ex;
        dinv[r * NN + n] = rsqrtf((float)(v + 1));
    }
    __syncthreads();
    ushort* csrb = csr + (size_t)r * EE + gbase;
    for (int idx = t; idx < NSEG * SCAP; idx += 256) {
        int s = idx / SCAP, i = idx - s * SCAP;
        if (i < scnt[s]) {
            uint e = segb[(size_t)s * NBK * SCAP + i];
            int p = atomicAdd(&lcur[e >> 16], 1);
            csrb[p] = (ushort)(e & 0xffffu);
        }
    }
}

// ---------------- MFMA GEMM1 (pair-batched): C[N][128] = A[N][256] x W1t[r]^T ----------------

__global__ __launch_bounds__(256) void k_mm1(const ushort* __restrict__ A,
                                             const ushort* __restrict__ W1t_all,
                                             ushort* __restrict__ C_all, int rbase) {
    int pr = blockIdx.y, r = rbase + pr;
    const ushort* Wt = W1t_all + (size_t)r * FF * HH;
    ushort* C = C_all + (size_t)pr * NN * HH;
    __shared__ __align__(16) ushort As[128 * 32];
    __shared__ __align__(16) ushort Bs[128 * 32];
    int tid = threadIdx.x;
    int lane = tid & 63, w = tid >> 6;
    int wm = w >> 1, wn = w & 1;
    int row0 = blockIdx.x * 128;
    int l15 = lane & 15, l4 = lane >> 4;

    f32x4 acc[4][4];
#pragma unroll
    for (int mf = 0; mf < 4; ++mf)
#pragma unroll
        for (int nf = 0; nf < 4; ++nf) acc[mf][nf] = (f32x4)0.f;

    for (int k0 = 0; k0 < FF; k0 += 32) {
#pragma unroll
        for (int i = 0; i < 2; ++i) {
            int chunk = i * 256 + tid;
            int ar = chunk >> 2, as_ = chunk & 3;
            int grow = row0 + ar; if (grow > NN - 1) grow = NN - 1;
            load_lds16(A + (size_t)grow * FF + k0 + as_ * 8,
                       As + (size_t)(i * 256 + w * 64) * 8);
        }
#pragma unroll
        for (int i = 0; i < 2; ++i) {
            int chunk = i * 256 + tid;
            int bn = chunk >> 2, slot = chunk & 3;
            uint4 v = *(const uint4*)(Wt + bn * FF + k0 + slot * 8);
            int sw = slot ^ ((bn >> 1) & 3);
            *(uint4*)(Bs + bn * 32 + sw * 8) = v;
        }
        __syncthreads();
        bf16x8 af[4], bfr[4];
#pragma unroll
        for (int mf = 0; mf < 4; ++mf) {
            int row = wm * 64 + mf * 16 + l15;
            af[mf] = *(const bf16x8*)(As + row * 32 + l4 * 8);
        }
#pragma unroll
        for (int nf = 0; nf < 4; ++nf) {
            int n = wn * 64 + nf * 16 + l15;
            int sw = l4 ^ ((n >> 1) & 3);
            bfr[nf] = *(const bf16x8*)(Bs + n * 32 + sw * 8);
        }
#pragma unroll
        for (int mf = 0; mf < 4; ++mf)
#pragma unroll
            for (int nf = 0; nf < 4; ++nf)
                acc[mf][nf] = __builtin_amdgcn_mfma_f32_16x16x32_bf16(af[mf], bfr[nf], acc[mf][nf], 0, 0, 0);
        __syncthreads();
    }
#pragma unroll
    for (int mf = 0; mf < 4; ++mf) {
#pragma unroll
        for (int nf = 0; nf < 4; ++nf) {
#pragma unroll
            for (int j = 0; j < 4; ++j) {
                int row = row0 + wm * 64 + mf * 16 + l4 * 4 + j;
                if (row < NN)
                    C[(size_t)row * HH + wn * 64 + nf * 16 + l15] = f2bf(acc[mf][nf][j]);
            }
        }
    }
}

// ---- MFMA GEMM2 (pair-batched; fused BN1+ReLU on bf16 A): C = relu(a*A+b) x W2t^T ----

__global__ __launch_bounds__(256) void k_mm2(const ushort* __restrict__ A_all,
                                             const float* __restrict__ ab_all,
                                             const ushort* __restrict__ W2t_all,
                                             ushort* __restrict__ C_all, int rbase) {
    int pr = blockIdx.y, r = rbase + pr;
    const ushort* A = A_all + (size_t)pr * NN * HH;
    const float* ab = ab_all + pr * 2 * HH;
    const ushort* Wt = W2t_all + (size_t)r * OO * HH;
    ushort* C = C_all + (size_t)pr * NN * OO;
    __shared__ __align__(16) ushort As[256 * 32];
    __shared__ __align__(16) ushort Ws2[32 * 128];
    int tid = threadIdx.x;
    int lane = tid & 63, w = tid >> 6;
    int l15 = lane & 15, l4 = lane >> 4;
    int row0 = blockIdx.x * 256;

#pragma unroll
    for (int i = 0; i < 2; ++i) {
        int chunk = i * 256 + tid;
        int n = chunk >> 4, slot = chunk & 15;
        uint4 v = *(const uint4*)(Wt + n * HH + slot * 8);
        int sw = slot ^ (n & 7);
        *(uint4*)(Ws2 + n * HH + sw * 8) = v;
    }

    f32x4 acc[4][2];
#pragma unroll
    for (int mf = 0; mf < 4; ++mf)
#pragma unroll
        for (int nf = 0; nf < 2; ++nf) acc[mf][nf] = (f32x4)0.f;

    for (int k0 = 0; k0 < HH; k0 += 32) {
#pragma unroll
        for (int i = 0; i < 4; ++i) {
            int chunk = i * 256 + tid;
            int ar = chunk >> 2, cg = chunk & 3;
            int grow = row0 + ar; if (grow > NN - 1) grow = NN - 1;
            uint4 xv = *(const uint4*)(A + (size_t)grow * HH + k0 + cg * 8);
            const float* aa = ab + k0 + cg * 8;
            float4 a0 = *(const float4*)aa;
            float4 a1 = *(const float4*)(aa + 4);
            const float* bp = ab + HH + k0 + cg * 8;
            float4 b0 = *(const float4*)bp;
            float4 b1 = *(const float4*)(bp + 4);
            float y0 = fmaxf(a0.x * bf2f((ushort)(xv.x & 0xffff)) + b0.x, 0.f);
            float y1 = fmaxf(a0.y * bf2f((ushort)(xv.x >> 16)) + b0.y, 0.f);
            float y2 = fmaxf(a0.z * bf2f((ushort)(xv.y & 0xffff)) + b0.z, 0.f);
            float y3 = fmaxf(a0.w * bf2f((ushort)(xv.y >> 16)) + b0.w, 0.f);
            float y4 = fmaxf(a1.x * bf2f((ushort)(xv.z & 0xffff)) + b1.x, 0.f);
            float y5 = fmaxf(a1.y * bf2f((ushort)(xv.z >> 16)) + b1.y, 0.f);
            float y6 = fmaxf(a1.z * bf2f((ushort)(xv.w & 0xffff)) + b1.z, 0.f);
            float y7 = fmaxf(a1.w * bf2f((ushort)(xv.w >> 16)) + b1.w, 0.f);
            uint4 o;
            o.x = (unsigned)f2bf(y0) | ((unsigned)f2bf(y1) << 16);
            o.y = (unsigned)f2bf(y2) | ((unsigned)f2bf(y3) << 16);
            o.z = (unsigned)f2bf(y4) | ((unsigned)f2bf(y5) << 16);
            o.w = (unsigned)f2bf(y6) | ((unsigned)f2bf(y7) << 16);
            *(uint4*)(As + chunk * 8) = o;
        }
        __syncthreads();
        bf16x8 af[4], bfr[2];
#pragma unroll
        for (int mf = 0; mf < 4; ++mf)
            af[mf] = *(const bf16x8*)(As + (w * 64 + mf * 16 + l15) * 32 + l4 * 8);
#pragma unroll
        for (int nf = 0; nf < 2; ++nf) {
            int n = nf * 16 + l15;
            int slot = (k0 >> 3) + l4;
            int sw = slot ^ (n & 7);
            bfr[nf] = *(const bf16x8*)(Ws2 + n * HH + sw * 8);
        }
#pragma unroll
        for (int mf = 0; mf < 4; ++mf)
#pragma unroll
            for (int nf = 0; nf < 2; ++nf)
                acc[mf][nf] = __builtin_amdgcn_mfma_f32_16x16x32_bf16(af[mf], bfr[nf], acc[mf][nf], 0, 0, 0);
        __syncthreads();
    }
#pragma unroll
    for (int mf = 0; mf < 4; ++mf) {
#pragma unroll
        for (int nf = 0; nf < 2; ++nf) {
#pragma unroll
            for (int j = 0; j < 4; ++j) {
                int row = row0 + w * 64 + mf * 16 + l4 * 4 + j;
                if (row < NN)
                    C[(size_t)row * OO + nf * 16 + l15] = f2bf(acc[mf][nf][j]);
            }
        }
    }
}

// ---------------- aggregation (pair-batched, bf16 in/out, 4x MLP unroll) ----------------

__global__ void k_agg1(const ushort* __restrict__ X_all, ushort* __restrict__ Y_all,
                       const int* __restrict__ offs_all, const ushort* __restrict__ csr_all,
                       const float* __restrict__ dinv_all, int rbase) {
    int pr = blockIdx.y, r = rbase + pr;
    const uint* Xu = (const uint*)(X_all + (size_t)pr * NN * HH);
    uint* Yu = (uint*)(Y_all + (size_t)pr * NN * HH);
    const int* offs = offs_all + r * (NN + 1);
    const ushort* csr = csr_all + (size_t)r * EE;
    const float* dinv = dinv_all + (size_t)r * NN;
    int tid = threadIdx.x;
    int wid = tid >> 6, lane = tid & 63;
    int n = blockIdx.x * 4 + wid;
    if (n >= NN) return;
    float ax = 0.f, ay = 0.f;
    int e = offs[n], s1 = offs[n + 1];
    for (; e + 4 <= s1; e += 4) {
        int sa = csr[e], sb = csr[e + 1], sc = csr[e + 2], sd = csr[e + 3];
        uint va = Xu[sa * 64 + lane];
        uint vb = Xu[sb * 64 + lane];
        uint vc = Xu[sc * 64 + lane];
        uint vd = Xu[sd * 64 + lane];
        float wa = dinv[sa], wb = dinv[sb], wc = dinv[sc], wd = dinv[sd];
        ax += wa * bf2f((ushort)(va & 0xffff)); ay += wa * bf2f((ushort)(va >> 16));
        ax += wb * bf2f((ushort)(vb & 0xffff)); ay += wb * bf2f((ushort)(vb >> 16));
        ax += wc * bf2f((ushort)(vc & 0xffff)); ay += wc * bf2f((ushort)(vc >> 16));
        ax += wd * bf2f((ushort)(vd & 0xffff)); ay += wd * bf2f((ushort)(vd >> 16));
    }
    for (; e < s1; ++e) {
        int s = csr[e];
        float w = dinv[s];
        uint v = Xu[s * 64 + lane];
        ax += w * bf2f((ushort)(v & 0xffff)); ay += w * bf2f((ushort)(v >> 16));
    }
    float dn = dinv[n];
    uint v = Xu[n * 64 + lane];
    ax += dn * bf2f((ushort)(v & 0xffff));
    ay += dn * bf2f((ushort)(v >> 16));
    Yu[n * 64 + lane] = (uint)f2bf(ax * dn) | ((uint)f2bf(ay * dn) << 16);
}

__global__ void k_agg2(const ushort* __restrict__ X_all, ushort* __restrict__ Y_all,
                       const int* __restrict__ offs_all, const ushort* __restrict__ csr_all,
                       const float* __restrict__ dinv_all, int rbase) {
    int pr = blockIdx.y, r = rbase + pr;
    const ushort* X = X_all + (size_t)pr * NN * OO;
    ushort* Y = Y_all + (size_t)pr * NN * OO;
    const int* offs = offs_all + r * (NN + 1);
    const ushort* csr = csr_all + (size_t)r * EE;
    const float* dinv = dinv_all + (size_t)r * NN;
    int tid = threadIdx.x;
    int wid = tid >> 6, lane = tid & 63;
    int sub = lane >> 5, col = lane & 31;
    int n = blockIdx.x * 8 + wid * 2 + sub;
    if (n >= NN) return;
    float acc = 0.f;
    int e = offs[n], s1 = offs[n + 1];
    for (; e + 4 <= s1; e += 4) {
        int sa = csr[e], sb = csr[e + 1], sc = csr[e + 2], sd = csr[e + 3];
        float xa = bf2f(X[sa * OO + col]);
        float xb = bf2f(X[sb * OO + col]);
        float xc = bf2f(X[sc * OO + col]);
        float xd = bf2f(X[sd * OO + col]);
        acc += dinv[sa] * xa + dinv[sb] * xb + dinv[sc] * xc + dinv[sd] * xd;
    }
    for (; e < s1; ++e) {
        int s = csr[e];
        acc += dinv[s] * bf2f(X[s * OO + col]);
    }
    float dn = dinv[n];
    acc += dn * bf2f(X[n * OO + col]);
    Y[(size_t)n * OO + col] = f2bf(acc * dn);
}

// ---------------- batchnorm stats (bf16 input, pair-batched) ----------------

template <int D>
__global__ void k_stats(const ushort* __restrict__ X_all, float* __restrict__ partial_all) {
    constexpr int BY = 256 / D;
    int pr = blockIdx.y;
    const ushort* X = X_all + (size_t)pr * NN * D;
    float* partial = partial_all + (size_t)pr * 256 * 2 * D;
    int c = threadIdx.x;
    int ty = threadIdx.y;
    float s = 0.f, ss = 0.f;
    for (int row = blockIdx.x * BY + ty; row < NN; row += 256 * BY) {
        float v = bf2f(X[(size_t)row * D + c]);
        s += v; ss += v * v;
    }
    __shared__ float ls[BY][D];
    __shared__ float lss[BY][D];
    ls[ty][c] = s; lss[ty][c] = ss;
    __syncthreads();
    if (ty == 0) {
#pragma unroll
        for (int y = 1; y < BY; ++y) { s += ls[y][c]; ss += lss[y][c]; }
        partial[blockIdx.x * 2 * D + c] = s;
        partial[blockIdx.x * 2 * D + D + c] = ss;
    }
}

template <int D>
__global__ void k_finalize(const float* __restrict__ partial_all, const float* __restrict__ g_all,
                           const float* __restrict__ be_all, float* __restrict__ ab_all, int rbase) {
    int pr = blockIdx.x, r = rbase + pr;
    const float* partial = partial_all + (size_t)pr * 256 * 2 * D;
    int c = threadIdx.x;
    float s = 0.f, ss = 0.f;
    for (int i = 0; i < 256; ++i) {
        s += partial[i * 2 * D + c];
        ss += partial[i * 2 * D + D + c];
    }
    float mean = s / (float)NN;
    float var = ss / (float)NN - mean * mean;
    float rstd = rsqrtf(var + EPSV);
    float a = g_all[r * D + c] * rstd;
    ab_all[pr * 2 * D + c] = a;
    ab_all[pr * 2 * D + D + c] = be_all[r * D + c] - mean * a;
}

// ---------------- gather + BN2-apply + ReLU + log_softmax (pair-batched) ----------------

__global__ void k_lsm(const ushort* __restrict__ X_all, const float* __restrict__ ab_all,
                      const int* __restrict__ batch, float* __restrict__ out, int rbase) {
    int pr = blockIdx.y, r = rbase + pr;
    const ushort* X = X_all + (size_t)pr * NN * OO;
    const float* ab = ab_all + pr * 2 * OO;
    int tx = threadIdx.x;  // 32 = OO
    int b = blockIdx.x * blockDim.y + threadIdx.y;
    if (b >= BB) return;
    int node = batch[b];
    float x = bf2f(X[(size_t)node * OO + tx]);
    float v = fmaxf(ab[tx] * x + ab[OO + tx], 0.f);
    float m = v;
#pragma unroll
    for (int off = 16; off; off >>= 1) m = fmaxf(m, __shfl_xor(m, off, 32));
    float e = expf(v - m);
    float sum = e;
#pragma unroll
    for (int off = 16; off; off >>= 1) sum += __shfl_xor(sum, off, 32);
    out[(size_t)b * (RR * OO) + r * OO + tx] = v - m - logf(sum);
}

// ---------------- host ----------------

extern "C" void kernel_launch(void* const* d_in, const int* in_sizes, int n_in,
                              void* d_out, int out_size, void* d_ws, size_t ws_size,
                              hipStream_t stream) {
    const float* features = (const float*)d_in[0];
    const int* edges = (const int*)d_in[1];
    const int* batch = (const int*)d_in[2];
    const float* W1 = (const float*)d_in[3];
    const float* g1 = (const float*)d_in[5];
    const float* be1 = (const float*)d_in[6];
    const float* W2 = (const float*)d_in[7];
    const float* g2 = (const float*)d_in[9];
    const float* be2 = (const float*)d_in[10];
    float* out = (float*)d_out;

    char* p = (char*)d_ws;
    auto carve = [&](size_t bytes) {
        void* q = (void*)p;
        p += (bytes + 255) & ~(size_t)255;
        return q;
    };
    ushort* Fbf = (ushort*)carve((size_t)NN * FF * 2);
    ushort* W1t = (ushort*)carve((size_t)RR * FF * HH * 2);
    ushort* W2t = (ushort*)carve((size_t)RR * HH * OO * 2);
    float* dinv = (float*)carve((size_t)RR * NN * 4);
    int* offs = (int*)carve((size_t)RR * (NN + 1) * 4);
    int* cnt = (int*)carve((size_t)RR * NSEG * NBK * 4);
    int* bbase = (int*)carve((size_t)RR * (NBK + 1) * 4);
    ushort* csr = (ushort*)carve((size_t)RR * EE * 2);
    ushort* bufAh = (ushort*)carve((size_t)PAIR * NN * HH * 2);
    ushort* bufB = (ushort*)carve((size_t)PAIR * NN * HH * 2);
    ushort* bufCh = (ushort*)carve((size_t)PAIR * NN * OO * 2);
    ushort* bufD = (ushort*)carve((size_t)PAIR * NN * OO * 2);
    float* partial = (float*)carve((size_t)PAIR * 256 * 2 * HH * 4);
    float* ab1 = (float*)carve((size_t)PAIR * 2 * HH * 4);
    float* ab2 = (float*)carve((size_t)PAIR * 2 * OO * 4);
    // seg staging (RR*NSEG*NBK*SCAP*4B = 37.75 MB) aliases bufAh+bufB (51.2 MB);
    // dead before bufAh is first written (mm1 runs after passB in-stream).
    uint* seg = (uint*)bufAh;

    k_cvt_feat<<<NN * FF / 8 / 256, 256, 0, stream>>>(features, Fbf);
    k_cvt_w<<<(RR * FF * HH + 255) / 256, 256, 0, stream>>>(W1, W2, W1t, W2t);

    k_passA<<<dim3(NSEG, RR), 256, 0, stream>>>(edges, seg, cnt);
    k_bbase<<<RR, 256, 0, stream>>>(cnt, bbase, offs);
    k_passB<<<dim3(NBK, RR), 256, 0, stream>>>(seg, cnt, bbase, csr, offs, dinv);

    for (int rbase = 0; rbase < RR; rbase += PAIR) {
        k_mm1<<<dim3((NN + 127) / 128, PAIR), 256, 0, stream>>>(Fbf, W1t, bufAh, rbase);
        k_agg1<<<dim3((NN + 3) / 4, PAIR), 256, 0, stream>>>(bufAh, bufB, offs, csr, dinv, rbase);
        k_stats<HH><<<dim3(256, PAIR), dim3(HH, 2), 0, stream>>>(bufB, partial);
        k_finalize<HH><<<PAIR, HH, 0, stream>>>(partial, g1, be1, ab1, rbase);

        k_mm2<<<dim3((NN + 255) / 256, PAIR), 256, 0, stream>>>(bufB, ab1, W2t, bufCh, rbase);
        k_agg2<<<dim3((NN + 7) / 8, PAIR), 256, 0, stream>>>(bufCh, bufD, offs, csr, dinv, rbase);
        k_stats<OO><<<dim3(256, PAIR), dim3(OO, 8), 0, stream>>>(bufD, partial);
        k_finalize<OO><<<PAIR, OO, 0, stream>>>(partial, g2, be2, ab2, rbase);

        k_lsm<<<dim3((BB + 7) / 8, PAIR), dim3(32, 8), 0, stream>>>(bufD, ab2, batch, out, rbase);
    }
}

// Round 9
// 520.081 us; speedup vs baseline: 4.7494x; 1.2239x over previous
//
#include <hip/hip_runtime.h>
#include <math.h>

#define NN 50000
#define EE 800000
#define RR 4
#define FF 256
#define HH 128
#define OO 32
#define BB 10000
#define EPSV 1e-5f

#define NSEG 256           // pass-A blocks per relation
#define CH   (EE / NSEG)   // 3125 edges per block
#define NBK  256           // node buckets
#define BNODE 196          // nodes per bucket (256*196 = 50176 >= NN)
#define SCAP 36            // per (block,bucket) cap; mean 12.2, ~ +7 sigma

typedef __bf16 bf16_t;
typedef __attribute__((ext_vector_type(8))) bf16_t bf16x8;
typedef __attribute__((ext_vector_type(4))) float f32x4;

__device__ __forceinline__ unsigned short f2bf(float f) {
    unsigned int u = __float_as_uint(f);
    u += 0x7fff + ((u >> 16) & 1);
    return (unsigned short)(u >> 16);
}
__device__ __forceinline__ float bf2f(unsigned short s) {
    return __uint_as_float(((unsigned int)s) << 16);
}
__device__ __forceinline__ void load_lds16(const void* g, void* l) {
    __builtin_amdgcn_global_load_lds(
        (const __attribute__((address_space(1))) unsigned int*)g,
        (__attribute__((address_space(3))) unsigned int*)l, 16, 0, 0);
}

// ---------------- conversions ----------------

__global__ void k_cvt_feat(const float* __restrict__ in, ushort* __restrict__ out) {
    int idx = blockIdx.x * 256 + threadIdx.x;
    const float4* p = (const float4*)in + (size_t)idx * 2;
    float4 a = p[0], b = p[1];
    uint4 o;
    o.x = (unsigned)f2bf(a.x) | ((unsigned)f2bf(a.y) << 16);
    o.y = (unsigned)f2bf(a.z) | ((unsigned)f2bf(a.w) << 16);
    o.z = (unsigned)f2bf(b.x) | ((unsigned)f2bf(b.y) << 16);
    o.w = (unsigned)f2bf(b.z) | ((unsigned)f2bf(b.w) << 16);
    ((uint4*)out)[idx] = o;
}

__global__ void k_cvt_w(const float* __restrict__ W1, const float* __restrict__ W2,
                        ushort* __restrict__ W1t, ushort* __restrict__ W2t) {
    int idx = blockIdx.x * 256 + threadIdx.x;
    if (idx < RR * FF * HH) {
        int r = idx >> 15, k = (idx >> 7) & 255, n = idx & 127;
        W1t[r * (HH * FF) + n * FF + k] = f2bf(W1[idx]);
    }
    if (idx < RR * HH * OO) {
        int r = idx >> 12, k = (idx >> 5) & 127, n = idx & 31;
        W2t[r * (OO * HH) + n * HH + k] = f2bf(W2[idx]);
    }
}

// ---------------- CSR build ----------------

__global__ __launch_bounds__(256) void k_passA(const int* __restrict__ edges,
                                               uint* __restrict__ seg,
                                               int* __restrict__ cnt) {
    int r = blockIdx.y, blk = blockIdx.x, t = threadIdx.x;
    __shared__ int lcur[NBK];
    lcur[t] = 0;
    __syncthreads();
    const int* srcp = edges + (size_t)r * 2 * EE + blk * CH;
    const int* dstp = srcp + EE;
    uint* segbase = seg + (size_t)(r * NSEG + blk) * NBK * SCAP;
    for (int i = t; i < CH; i += 256) {
        int s = srcp[i], d = dstp[i];
        int b = d / BNODE;
        int dloc = d - b * BNODE;
        int pos = atomicAdd(&lcur[b], 1);
        if (pos < SCAP) segbase[b * SCAP + pos] = (uint)s | ((uint)dloc << 16);
    }
    __syncthreads();
    cnt[(r * NSEG + blk) * NBK + t] = min(lcur[t], SCAP);
}

__global__ void k_bbase(const int* __restrict__ cnt, int* __restrict__ bbase,
                        int* __restrict__ offs) {
    int r = blockIdx.x, t = threadIdx.x;
    int sum = 0;
    for (int s = 0; s < NSEG; ++s) sum += cnt[(r * NSEG + s) * NBK + t];
    __shared__ int sh[256];
    sh[t] = sum;
    __syncthreads();
    for (int off = 1; off < 256; off <<= 1) {
        int u = (t >= off) ? sh[t - off] : 0;
        __syncthreads();
        sh[t] += u;
        __syncthreads();
    }
    bbase[r * (NBK + 1) + t] = sh[t] - sum;
    if (t == 255) {
        bbase[r * (NBK + 1) + NBK] = sh[t];
        offs[r * (NN + 1) + NN] = sh[t];
    }
}

__global__ __launch_bounds__(256) void k_passB(const uint* __restrict__ seg,
                                               const int* __restrict__ cnt,
                                               const int* __restrict__ bbase,
                                               ushort* __restrict__ csr,
                                               int* __restrict__ offs,
                                               float* __restrict__ dinv) {
    int b = blockIdx.x, r = blockIdx.y, t = threadIdx.x;
    __shared__ int ldeg[256];
    __shared__ int lcur[256];
    __shared__ int sh[256];
    __shared__ int scnt[NSEG];
    ldeg[t] = 0;
    scnt[t] = cnt[(r * NSEG + t) * NBK + b];
    __syncthreads();
    const uint* segb = seg + (size_t)(r * NSEG) * NBK * SCAP + (size_t)b * SCAP;
    for (int idx = t; idx < NSEG * SCAP; idx += 256) {
        int s = idx / SCAP, i = idx - s * SCAP;
        if (i < scnt[s])
            atomicAdd(&ldeg[segb[(size_t)s * NBK * SCAP + i] >> 16], 1);
    }
    __syncthreads();
    int v = ldeg[t];
    sh[t] = v;
    __syncthreads();
    for (int off = 1; off < 256; off <<= 1) {
        int u = (t >= off) ? sh[t - off] : 0;
        __syncthreads();
        sh[t] += u;
        __syncthreads();
    }
    int ex = sh[t] - v;
    lcur[t] = ex;
    int gbase = bbase[r * (NBK + 1) + b];
    int n0 = b * BNODE;
    int n = n0 + t;
    if (t < BNODE && n < NN) {
        offs[r * (NN + 1) + n] = gbase + ex;
        dinv[r * NN + n] = rsqrtf((float)(v + 1));
    }
    __syncthreads();
    ushort* csrb = csr + (size_t)r * EE + gbase;
    for (int idx = t; idx < NSEG * SCAP; idx += 256) {
        int s = idx / SCAP, i = idx - s * SCAP;
        if (i < scnt[s]) {
            uint e = segb[(size_t)s * NBK * SCAP + i];
            int p = atomicAdd(&lcur[e >> 16], 1);
            csrb[p] = (ushort)(e & 0xffffu);
        }
    }
}

// ---------------- MFMA GEMM1 (rel-batched): C[N][128] = A[N][256] x W1t[r]^T ----------------

__global__ __launch_bounds__(256) void k_mm1(const ushort* __restrict__ A,
                                             const ushort* __restrict__ W1t_all,
                                             ushort* __restrict__ C_all, int rbase) {
    int pr = blockIdx.y, r = rbase + pr;
    const ushort* Wt = W1t_all + (size_t)r * FF * HH;
    ushort* C = C_all + (size_t)pr * NN * HH;
    __shared__ __align__(16) ushort As[128 * 32];
    __shared__ __align__(16) ushort Bs[128 * 32];
    int tid = threadIdx.x;
    int lane = tid & 63, w = tid >> 6;
    int wm = w >> 1, wn = w & 1;
    int row0 = blockIdx.x * 128;
    int l15 = lane & 15, l4 = lane >> 4;

    f32x4 acc[4][4];
#pragma unroll
    for (int mf = 0; mf < 4; ++mf)
#pragma unroll
        for (int nf = 0; nf < 4; ++nf) acc[mf][nf] = (f32x4)0.f;

    for (int k0 = 0; k0 < FF; k0 += 32) {
#pragma unroll
        for (int i = 0; i < 2; ++i) {
            int chunk = i * 256 + tid;
            int ar = chunk >> 2, as_ = chunk & 3;
            int grow = row0 + ar; if (grow > NN - 1) grow = NN - 1;
            load_lds16(A + (size_t)grow * FF + k0 + as_ * 8,
                       As + (size_t)(i * 256 + w * 64) * 8);
        }
#pragma unroll
        for (int i = 0; i < 2; ++i) {
            int chunk = i * 256 + tid;
            int bn = chunk >> 2, slot = chunk & 3;
            uint4 v = *(const uint4*)(Wt + bn * FF + k0 + slot * 8);
            int sw = slot ^ ((bn >> 1) & 3);
            *(uint4*)(Bs + bn * 32 + sw * 8) = v;
        }
        __syncthreads();
        bf16x8 af[4], bfr[4];
#pragma unroll
        for (int mf = 0; mf < 4; ++mf) {
            int row = wm * 64 + mf * 16 + l15;
            af[mf] = *(const bf16x8*)(As + row * 32 + l4 * 8);
        }
#pragma unroll
        for (int nf = 0; nf < 4; ++nf) {
            int n = wn * 64 + nf * 16 + l15;
            int sw = l4 ^ ((n >> 1) & 3);
            bfr[nf] = *(const bf16x8*)(Bs + n * 32 + sw * 8);
        }
#pragma unroll
        for (int mf = 0; mf < 4; ++mf)
#pragma unroll
            for (int nf = 0; nf < 4; ++nf)
                acc[mf][nf] = __builtin_amdgcn_mfma_f32_16x16x32_bf16(af[mf], bfr[nf], acc[mf][nf], 0, 0, 0);
        __syncthreads();
    }
#pragma unroll
    for (int mf = 0; mf < 4; ++mf) {
#pragma unroll
        for (int nf = 0; nf < 4; ++nf) {
#pragma unroll
            for (int j = 0; j < 4; ++j) {
                int row = row0 + wm * 64 + mf * 16 + l4 * 4 + j;
                if (row < NN)
                    C[(size_t)row * HH + wn * 64 + nf * 16 + l15] = f2bf(acc[mf][nf][j]);
            }
        }
    }
}

// ---- MFMA GEMM2 (rel-batched; fused BN1+ReLU on bf16 A): C = relu(a*A+b) x W2t^T ----

__global__ __launch_bounds__(256) void k_mm2(const ushort* __restrict__ A_all,
                                             const float* __restrict__ ab_all,
                                             const ushort* __restrict__ W2t_all,
                                             ushort* __restrict__ C_all, int rbase) {
    int pr = blockIdx.y, r = rbase + pr;
    const ushort* A = A_all + (size_t)pr * NN * HH;
    const float* ab = ab_all + pr * 2 * HH;
    const ushort* Wt = W2t_all + (size_t)r * OO * HH;
    ushort* C = C_all + (size_t)pr * NN * OO;
    __shared__ __align__(16) ushort As[256 * 32];
    __shared__ __align__(16) ushort Ws2[32 * 128];
    int tid = threadIdx.x;
    int lane = tid & 63, w = tid >> 6;
    int l15 = lane & 15, l4 = lane >> 4;
    int row0 = blockIdx.x * 256;

#pragma unroll
    for (int i = 0; i < 2; ++i) {
        int chunk = i * 256 + tid;
        int n = chunk >> 4, slot = chunk & 15;
        uint4 v = *(const uint4*)(Wt + n * HH + slot * 8);
        int sw = slot ^ (n & 7);
        *(uint4*)(Ws2 + n * HH + sw * 8) = v;
    }

    f32x4 acc[4][2];
#pragma unroll
    for (int mf = 0; mf < 4; ++mf)
#pragma unroll
        for (int nf = 0; nf < 2; ++nf) acc[mf][nf] = (f32x4)0.f;

    for (int k0 = 0; k0 < HH; k0 += 32) {
#pragma unroll
        for (int i = 0; i < 4; ++i) {
            int chunk = i * 256 + tid;
            int ar = chunk >> 2, cg = chunk & 3;
            int grow = row0 + ar; if (grow > NN - 1) grow = NN - 1;
            uint4 xv = *(const uint4*)(A + (size_t)grow * HH + k0 + cg * 8);
            const float* aa = ab + k0 + cg * 8;
            float4 a0 = *(const float4*)aa;
            float4 a1 = *(const float4*)(aa + 4);
            const float* bp = ab + HH + k0 + cg * 8;
            float4 b0 = *(const float4*)bp;
            float4 b1 = *(const float4*)(bp + 4);
            float y0 = fmaxf(a0.x * bf2f((ushort)(xv.x & 0xffff)) + b0.x, 0.f);
            float y1 = fmaxf(a0.y * bf2f((ushort)(xv.x >> 16)) + b0.y, 0.f);
            float y2 = fmaxf(a0.z * bf2f((ushort)(xv.y & 0xffff)) + b0.z, 0.f);
            float y3 = fmaxf(a0.w * bf2f((ushort)(xv.y >> 16)) + b0.w, 0.f);
            float y4 = fmaxf(a1.x * bf2f((ushort)(xv.z & 0xffff)) + b1.x, 0.f);
            float y5 = fmaxf(a1.y * bf2f((ushort)(xv.z >> 16)) + b1.y, 0.f);
            float y6 = fmaxf(a1.z * bf2f((ushort)(xv.w & 0xffff)) + b1.z, 0.f);
            float y7 = fmaxf(a1.w * bf2f((ushort)(xv.w >> 16)) + b1.w, 0.f);
            uint4 o;
            o.x = (unsigned)f2bf(y0) | ((unsigned)f2bf(y1) << 16);
            o.y = (unsigned)f2bf(y2) | ((unsigned)f2bf(y3) << 16);
            o.z = (unsigned)f2bf(y4) | ((unsigned)f2bf(y5) << 16);
            o.w = (unsigned)f2bf(y6) | ((unsigned)f2bf(y7) << 16);
            *(uint4*)(As + chunk * 8) = o;
        }
        __syncthreads();
        bf16x8 af[4], bfr[2];
#pragma unroll
        for (int mf = 0; mf < 4; ++mf)
            af[mf] = *(const bf16x8*)(As + (w * 64 + mf * 16 + l15) * 32 + l4 * 8);
#pragma unroll
        for (int nf = 0; nf < 2; ++nf) {
            int n = nf * 16 + l15;
            int slot = (k0 >> 3) + l4;
            int sw = slot ^ (n & 7);
            bfr[nf] = *(const bf16x8*)(Ws2 + n * HH + sw * 8);
        }
#pragma unroll
        for (int mf = 0; mf < 4; ++mf)
#pragma unroll
            for (int nf = 0; nf < 2; ++nf)
                acc[mf][nf] = __builtin_amdgcn_mfma_f32_16x16x32_bf16(af[mf], bfr[nf], acc[mf][nf], 0, 0, 0);
        __syncthreads();
    }
#pragma unroll
    for (int mf = 0; mf < 4; ++mf) {
#pragma unroll
        for (int nf = 0; nf < 2; ++nf) {
#pragma unroll
            for (int j = 0; j < 4; ++j) {
                int row = row0 + w * 64 + mf * 16 + l4 * 4 + j;
                if (row < NN)
                    C[(size_t)row * OO + nf * 16 + l15] = f2bf(acc[mf][nf][j]);
            }
        }
    }
}

// ---------------- aggregation (rel-batched, bf16 in/out, 8x MLP unroll) ----------------

__global__ void k_agg1(const ushort* __restrict__ X_all, ushort* __restrict__ Y_all,
                       const int* __restrict__ offs_all, const ushort* __restrict__ csr_all,
                       const float* __restrict__ dinv_all, int rbase) {
    int pr = blockIdx.y, r = rbase + pr;
    const uint* Xu = (const uint*)(X_all + (size_t)pr * NN * HH);
    uint* Yu = (uint*)(Y_all + (size_t)pr * NN * HH);
    const int* offs = offs_all + r * (NN + 1);
    const ushort* csr = csr_all + (size_t)r * EE;
    const float* dinv = dinv_all + (size_t)r * NN;
    int tid = threadIdx.x;
    int wid = tid >> 6, lane = tid & 63;
    int n = blockIdx.x * 4 + wid;
    if (n >= NN) return;
    float ax = 0.f, ay = 0.f;
    int e = offs[n], s1 = offs[n + 1];
    for (; e + 8 <= s1; e += 8) {
        int ia = csr[e], ib = csr[e + 1], ic = csr[e + 2], id = csr[e + 3];
        int ie = csr[e + 4], if_ = csr[e + 5], ig = csr[e + 6], ih = csr[e + 7];
        uint va = Xu[ia * 64 + lane], vb = Xu[ib * 64 + lane];
        uint vc = Xu[ic * 64 + lane], vd = Xu[id * 64 + lane];
        uint ve = Xu[ie * 64 + lane], vf = Xu[if_ * 64 + lane];
        uint vg = Xu[ig * 64 + lane], vh = Xu[ih * 64 + lane];
        float wa = dinv[ia], wb = dinv[ib], wc = dinv[ic], wd = dinv[id];
        float we = dinv[ie], wf = dinv[if_], wg = dinv[ig], wh = dinv[ih];
        ax += wa * bf2f((ushort)(va & 0xffff)); ay += wa * bf2f((ushort)(va >> 16));
        ax += wb * bf2f((ushort)(vb & 0xffff)); ay += wb * bf2f((ushort)(vb >> 16));
        ax += wc * bf2f((ushort)(vc & 0xffff)); ay += wc * bf2f((ushort)(vc >> 16));
        ax += wd * bf2f((ushort)(vd & 0xffff)); ay += wd * bf2f((ushort)(vd >> 16));
        ax += we * bf2f((ushort)(ve & 0xffff)); ay += we * bf2f((ushort)(ve >> 16));
        ax += wf * bf2f((ushort)(vf & 0xffff)); ay += wf * bf2f((ushort)(vf >> 16));
        ax += wg * bf2f((ushort)(vg & 0xffff)); ay += wg * bf2f((ushort)(vg >> 16));
        ax += wh * bf2f((ushort)(vh & 0xffff)); ay += wh * bf2f((ushort)(vh >> 16));
    }
    for (; e + 4 <= s1; e += 4) {
        int ia = csr[e], ib = csr[e + 1], ic = csr[e + 2], id = csr[e + 3];
        uint va = Xu[ia * 64 + lane], vb = Xu[ib * 64 + lane];
        uint vc = Xu[ic * 64 + lane], vd = Xu[id * 64 + lane];
        float wa = dinv[ia], wb = dinv[ib], wc = dinv[ic], wd = dinv[id];
        ax += wa * bf2f((ushort)(va & 0xffff)); ay += wa * bf2f((ushort)(va >> 16));
        ax += wb * bf2f((ushort)(vb & 0xffff)); ay += wb * bf2f((ushort)(vb >> 16));
        ax += wc * bf2f((ushort)(vc & 0xffff)); ay += wc * bf2f((ushort)(vc >> 16));
        ax += wd * bf2f((ushort)(vd & 0xffff)); ay += wd * bf2f((ushort)(vd >> 16));
    }
    for (; e < s1; ++e) {
        int s = csr[e];
        float w = dinv[s];
        uint v = Xu[s * 64 + lane];
        ax += w * bf2f((ushort)(v & 0xffff)); ay += w * bf2f((ushort)(v >> 16));
    }
    float dn = dinv[n];
    uint v = Xu[n * 64 + lane];
    ax += dn * bf2f((ushort)(v & 0xffff));
    ay += dn * bf2f((ushort)(v >> 16));
    Yu[n * 64 + lane] = (uint)f2bf(ax * dn) | ((uint)f2bf(ay * dn) << 16);
}

__global__ void k_agg2(const ushort* __restrict__ X_all, ushort* __restrict__ Y_all,
                       const int* __restrict__ offs_all, const ushort* __restrict__ csr_all,
                       const float* __restrict__ dinv_all, int rbase) {
    int pr = blockIdx.y, r = rbase + pr;
    const ushort* X = X_all + (size_t)pr * NN * OO;
    ushort* Y = Y_all + (size_t)pr * NN * OO;
    const int* offs = offs_all + r * (NN + 1);
    const ushort* csr = csr_all + (size_t)r * EE;
    const float* dinv = dinv_all + (size_t)r * NN;
    int tid = threadIdx.x;
    int wid = tid >> 6, lane = tid & 63;
    int sub = lane >> 5, col = lane & 31;
    int n = blockIdx.x * 8 + wid * 2 + sub;
    if (n >= NN) return;
    float acc = 0.f;
    int e = offs[n], s1 = offs[n + 1];
    for (; e + 8 <= s1; e += 8) {
        int ia = csr[e], ib = csr[e + 1], ic = csr[e + 2], id = csr[e + 3];
        int ie = csr[e + 4], if_ = csr[e + 5], ig = csr[e + 6], ih = csr[e + 7];
        float xa = bf2f(X[ia * OO + col]), xb = bf2f(X[ib * OO + col]);
        float xc = bf2f(X[ic * OO + col]), xd = bf2f(X[id * OO + col]);
        float xe = bf2f(X[ie * OO + col]), xf = bf2f(X[if_ * OO + col]);
        float xg = bf2f(X[ig * OO + col]), xh = bf2f(X[ih * OO + col]);
        acc += dinv[ia] * xa + dinv[ib] * xb + dinv[ic] * xc + dinv[id] * xd;
        acc += dinv[ie] * xe + dinv[if_] * xf + dinv[ig] * xg + dinv[ih] * xh;
    }
    for (; e + 4 <= s1; e += 4) {
        int ia = csr[e], ib = csr[e + 1], ic = csr[e + 2], id = csr[e + 3];
        float xa = bf2f(X[ia * OO + col]), xb = bf2f(X[ib * OO + col]);
        float xc = bf2f(X[ic * OO + col]), xd = bf2f(X[id * OO + col]);
        acc += dinv[ia] * xa + dinv[ib] * xb + dinv[ic] * xc + dinv[id] * xd;
    }
    for (; e < s1; ++e) {
        int s = csr[e];
        acc += dinv[s] * bf2f(X[s * OO + col]);
    }
    float dn = dinv[n];
    acc += dn * bf2f(X[n * OO + col]);
    Y[(size_t)n * OO + col] = f2bf(acc * dn);
}

// ---------------- batchnorm stats (bf16 input, vectorized, rel-batched) ----------------

template <int D>
__global__ void k_stats(const ushort* __restrict__ X_all, float* __restrict__ partial_all) {
    constexpr int CW = D / 2;       // uint columns
    constexpr int BY = 512 / D;     // rows per block slice (CW*BY = 256 threads)
    int pr = blockIdx.y;
    const uint* X = (const uint*)(X_all + (size_t)pr * NN * D);
    float* partial = partial_all + (size_t)pr * 256 * 2 * D;
    int c = threadIdx.x;
    int ty = threadIdx.y;
    float s0 = 0.f, ss0 = 0.f, s1 = 0.f, ss1 = 0.f;
    for (int row = blockIdx.x * BY + ty; row < NN; row += 256 * BY) {
        uint v = X[(size_t)row * CW + c];
        float a = bf2f((ushort)(v & 0xffff)), b = bf2f((ushort)(v >> 16));
        s0 += a; ss0 += a * a; s1 += b; ss1 += b * b;
    }
    __shared__ float ls[BY][2][CW];
    __shared__ float lss[BY][2][CW];
    ls[ty][0][c] = s0; ls[ty][1][c] = s1;
    lss[ty][0][c] = ss0; lss[ty][1][c] = ss1;
    __syncthreads();
    if (ty == 0) {
#pragma unroll
        for (int y = 1; y < BY; ++y) {
            s0 += ls[y][0][c]; s1 += ls[y][1][c];
            ss0 += lss[y][0][c]; ss1 += lss[y][1][c];
        }
        partial[blockIdx.x * 2 * D + 2 * c] = s0;
        partial[blockIdx.x * 2 * D + 2 * c + 1] = s1;
        partial[blockIdx.x * 2 * D + D + 2 * c] = ss0;
        partial[blockIdx.x * 2 * D + D + 2 * c + 1] = ss1;
    }
}

template <int D>
__global__ void k_finalize(const float* __restrict__ partial_all, const float* __restrict__ g_all,
                           const float* __restrict__ be_all, float* __restrict__ ab_all, int rbase) {
    int pr = blockIdx.x, r = rbase + pr;
    const float* partial = partial_all + (size_t)pr * 256 * 2 * D;
    int c = threadIdx.x;
    float s = 0.f, ss = 0.f;
    for (int i = 0; i < 256; ++i) {
        s += partial[i * 2 * D + c];
        ss += partial[i * 2 * D + D + c];
    }
    float mean = s / (float)NN;
    float var = ss / (float)NN - mean * mean;
    float rstd = rsqrtf(var + EPSV);
    float a = g_all[r * D + c] * rstd;
    ab_all[pr * 2 * D + c] = a;
    ab_all[pr * 2 * D + D + c] = be_all[r * D + c] - mean * a;
}

// ---------------- gather + BN2-apply + ReLU + log_softmax (rel-batched) ----------------

__global__ void k_lsm(const ushort* __restrict__ X_all, const float* __restrict__ ab_all,
                      const int* __restrict__ batch, float* __restrict__ out, int rbase) {
    int pr = blockIdx.y, r = rbase + pr;
    const ushort* X = X_all + (size_t)pr * NN * OO;
    const float* ab = ab_all + pr * 2 * OO;
    int tx = threadIdx.x;  // 32 = OO
    int b = blockIdx.x * blockDim.y + threadIdx.y;
    if (b >= BB) return;
    int node = batch[b];
    float x = bf2f(X[(size_t)node * OO + tx]);
    float v = fmaxf(ab[tx] * x + ab[OO + tx], 0.f);
    float m = v;
#pragma unroll
    for (int off = 16; off; off >>= 1) m = fmaxf(m, __shfl_xor(m, off, 32));
    float e = expf(v - m);
    float sum = e;
#pragma unroll
    for (int off = 16; off; off >>= 1) sum += __shfl_xor(sum, off, 32);
    out[(size_t)b * (RR * OO) + r * OO + tx] = v - m - logf(sum);
}

// ---------------- host ----------------

extern "C" void kernel_launch(void* const* d_in, const int* in_sizes, int n_in,
                              void* d_out, int out_size, void* d_ws, size_t ws_size,
                              hipStream_t stream) {
    const float* features = (const float*)d_in[0];
    const int* edges = (const int*)d_in[1];
    const int* batch = (const int*)d_in[2];
    const float* W1 = (const float*)d_in[3];
    const float* g1 = (const float*)d_in[5];
    const float* be1 = (const float*)d_in[6];
    const float* W2 = (const float*)d_in[7];
    const float* g2 = (const float*)d_in[9];
    const float* be2 = (const float*)d_in[10];
    float* out = (float*)d_out;

    char* p = (char*)d_ws;
    auto carve = [&](size_t bytes) {
        void* q = (void*)p;
        p += (bytes + 255) & ~(size_t)255;
        return q;
    };
    ushort* Fbf = (ushort*)carve((size_t)NN * FF * 2);
    ushort* W1t = (ushort*)carve((size_t)RR * FF * HH * 2);
    ushort* W2t = (ushort*)carve((size_t)RR * HH * OO * 2);
    float* dinv = (float*)carve((size_t)RR * NN * 4);
    int* offs = (int*)carve((size_t)RR * (NN + 1) * 4);
    int* cnt = (int*)carve((size_t)RR * NSEG * NBK * 4);
    int* bbase = (int*)carve((size_t)RR * (NBK + 1) * 4);
    ushort* csr = (ushort*)carve((size_t)RR * EE * 2);

    size_t fixed = (size_t)(p - (char*)d_ws);
    // PR=4 extra: bufAh+bufB (2*4*12.8MB) + partial/ab + slack (bufCh/D alias Fbf)
    size_t need4 = fixed + 2 * (size_t)4 * NN * HH * 2 + (size_t)4 * 256 * 2 * HH * 4 + (1 << 20);
    int PR = (ws_size >= need4) ? 4 : 2;

    ushort* bufAh = (ushort*)carve((size_t)PR * NN * HH * 2);
    ushort* bufB = (ushort*)carve((size_t)PR * NN * HH * 2);
    ushort* bufCh;
    ushort* bufD;
    if (PR == 4) {
        // Fbf (25.6 MB) is dead after mm1 (all relations) -> reuse for bufCh+bufD
        bufCh = Fbf;
        bufD = Fbf + (size_t)4 * NN * OO;
    } else {
        bufCh = (ushort*)carve((size_t)PR * NN * OO * 2);
        bufD = (ushort*)carve((size_t)PR * NN * OO * 2);
    }
    float* partial = (float*)carve((size_t)PR * 256 * 2 * HH * 4);
    float* ab1 = (float*)carve((size_t)PR * 2 * HH * 4);
    float* ab2 = (float*)carve((size_t)PR * 2 * OO * 4);
    // seg staging (37.75 MB) aliases bufAh(+bufB): PR=4 -> 51.2 MB; PR=2 -> 25.6+25.6 contiguous.
    uint* seg = (uint*)bufAh;

    k_cvt_feat<<<NN * FF / 8 / 256, 256, 0, stream>>>(features, Fbf);
    k_cvt_w<<<(RR * FF * HH + 255) / 256, 256, 0, stream>>>(W1, W2, W1t, W2t);

    k_passA<<<dim3(NSEG, RR), 256, 0, stream>>>(edges, seg, cnt);
    k_bbase<<<RR, 256, 0, stream>>>(cnt, bbase, offs);
    k_passB<<<dim3(NBK, RR), 256, 0, stream>>>(seg, cnt, bbase, csr, offs, dinv);

    for (int rbase = 0; rbase < RR; rbase += PR) {
        k_mm1<<<dim3((NN + 127) / 128, PR), 256, 0, stream>>>(Fbf, W1t, bufAh, rbase);
        k_agg1<<<dim3((NN + 3) / 4, PR), 256, 0, stream>>>(bufAh, bufB, offs, csr, dinv, rbase);
        k_stats<HH><<<dim3(256, PR), dim3(HH / 2, 512 / HH), 0, stream>>>(bufB, partial);
        k_finalize<HH><<<PR, HH, 0, stream>>>(partial, g1, be1, ab1, rbase);

        k_mm2<<<dim3((NN + 255) / 256, PR), 256, 0, stream>>>(bufB, ab1, W2t, bufCh, rbase);
        k_agg2<<<dim3((NN + 7) / 8, PR), 256, 0, stream>>>(bufCh, bufD, offs, csr, dinv, rbase);
        k_stats<OO><<<dim3(256, PR), dim3(OO / 2, 512 / OO), 0, stream>>>(bufD, partial);
        k_finalize<OO><<<PR, OO, 0, stream>>>(partial, g2, be2, ab2, rbase);

        k_lsm<<<dim3((BB + 7) / 8, PR), dim3(32, 8), 0, stream>>>(bufD, ab2, batch, out, rbase);
    }
}